// Round 11
// baseline (435.232 us; speedup 1.0000x reference)
//
#include <hip/hip_runtime.h>
#include <hip/hip_fp16.h>

// ---------------- problem constants ----------------
#define NI 3
#define NS 32
#define CHN 512
#define OH 23
#define P2 529          // 23*23
#define NP 50784        // NI*NS*P2
#define UV 484          // 22*22
#define WSZ 262144      // NS*CHN*16
#define KTOT 1536       // 3n * 512 (uv padded 484->512)
#define NKB 48          // KTOT/32 k-blocks
#define RSP 1544        // Rs LDS pitch in halves (16B-aligned rows, bank-stagger)

typedef unsigned int uint32;
typedef unsigned short u16;
typedef _Float16 h2 __attribute__((ext_vector_type(2)));
typedef _Float16 f16x8 __attribute__((ext_vector_type(8)));
typedef float f32x4 __attribute__((ext_vector_type(4)));

// ---------------- workspace layout (bytes) ----------------
// featT layout: [snT(96)][cb4(4)][uv(484)][c(128)] f16, snT = s*3+n
// featC layout (k-blocked): [s(32)][kb(48)][c(512)][32] f16, k = kb*32+kk = n*512+uv
//   (uv 484..511 zero). Written by k_adjoint t=0 as a byproduct; read t>=1.
#define OFF_FEATT 0UL           // 23,789,568 halves = 47,579,136 B
#define OFF_LABEL 47579136UL    // 50784 f32
#define OFF_S0    47782272UL    // 50784 f32 (scores partial A / merged ping)
#define OFF_S1    47985408UL    // 50784 f32 (merged pong)
#define OFF_SGRAW 48188544UL    // 50784 f32 (A*wg raw, partial A)
#define OFF_WG    48391680UL    // 262144 f32
#define OFF_WGF16 49440256UL    // 262144 f16, layout [s][tap][c]
#define OFF_W0F16 49964544UL    // 262144 f16, layout [s][tap][c]
#define OFF_PART  50488832UL    // partial-sum arrays (float), ~33 KB
#define OFF_FEATC 50521600UL    // 32*48*512*32 f16 = 50,331,648 B
#define OFF_S0B   100853248UL   // 50784 f32 (scores partial B)
#define OFF_SGB   101056384UL   // 50784 f32 (A*wg raw, partial B)

// partial-array float indices — each slot written by exactly ONE block (ticket is the
// only atomic; it orders, values stay single-writer deterministic).
#define P_NUM   4320    // [5][32][8]  : per-(t,s,chunk) sum wg^2 partials
#define P_LOSS  5600    // [5][32]     : per-(t,s) residual-loss partials
#define P_WSQ0  5760    // [32]        : sum w0^2 per s
#define P_WSQA  5792    // [4][32][8]  : sum w_t^2 partials, t=1..4
#define P_WSQ5  6816    // [1024]      : sum w5^2 per block
#define P_L5    7840    // [199]       : final loss per block
#define P_TICKET 8064   // uint32 ticket for last-block losses fold

__device__ __forceinline__ float waveSum(float v) {
#pragma unroll
  for (int o = 32; o > 0; o >>= 1) v += __shfl_xor(v, o, 64);
  return v;
}

// ---------------- setup: feat->f16 transpose to featT, + w, label --------------------
// transpose tile = (snT, cb of 64 ch, uvh of 242 uv): LDS [64 c][121 u32-pairs] = 31 KB
// grid = 1536 (tiles) + 32 (w) + 199 (label) = 1767 blocks x 256
__global__ __launch_bounds__(256) void k_setup(const float* __restrict__ feat,
                                               const float* __restrict__ w0,
                                               const float* __restrict__ bb,
                                               u16* __restrict__ featT,
                                               u16* __restrict__ w0f16,
                                               float* __restrict__ wmaster,
                                               float* __restrict__ label,
                                               float* __restrict__ part) {
  __shared__ uint32 lds32[64 * 121];  // [64 c][242 uv] f16 as u32 pairs, pitch 121
  __shared__ float sred[4];
  int b = blockIdx.x, tid = threadIdx.x;
  if (b < 1536) {
    int snT = b >> 4, r4 = b & 15;
    int cb = r4 >> 1, uvh = r4 & 1;  // 64-ch group, 242-uv half
    int s = snT / 3, n = snT % 3;
    const float* fsrc =
        feat + ((size_t)n * NS + s) * CHN * UV + (size_t)(cb * 64) * UV + uvh * 242;
#pragma unroll
    for (int it = 0; it < 31; ++it) {
      int idx = it * 256 + tid;
      if (idx < 7744) {
        int r = (unsigned)idx / 121u;
        int j = idx - r * 121;
        float2 v = *(const float2*)(fsrc + (size_t)r * UV + 2 * j);
        lds32[idx] = (uint32)__half_as_ushort(__float2half(v.x)) |
                     ((uint32)__half_as_ushort(__float2half(v.y)) << 16);
      }
    }
    __syncthreads();
    uint32* dstT = (uint32*)featT +
                   ((size_t)(snT * 4 + (cb >> 1)) * UV + uvh * 242) * 64 + (cb & 1) * 32;
#pragma unroll
    for (int it = 0; it < 16; ++it) {
      int o = it * 256 + tid;
      if (o < 3872) {
        int uv = o >> 4, kp = o & 15;
        int j = uv >> 1, sh = (uv & 1) * 16;
        uint32 a0 = lds32[(4 * kp + 0) * 121 + j];
        uint32 a1 = lds32[(4 * kp + 1) * 121 + j];
        uint32 a2 = lds32[(4 * kp + 2) * 121 + j];
        uint32 a3 = lds32[(4 * kp + 3) * 121 + j];
        uint2 val;
        val.x = ((a0 >> sh) & 0xffffu) | (((a1 >> sh) & 0xffffu) << 16);
        val.y = ((a2 >> sh) & 0xffffu) | (((a3 >> sh) & 0xffffu) << 16);
        *(uint2*)(dstT + (size_t)uv * 64 + 2 * kp) = val;
      }
    }
  } else if (b < 1568) {
    int s = b - 1536;
    if (b == 1536 && tid == 0) ((uint32*)part)[P_TICKET] = 0;  // ticket reset
    for (int i = tid; i < 8192; i += 256) {
      int tap = i >> 9, c = i & 511;
      w0f16[(size_t)s * 8192 + i] =
          __half_as_ushort(__float2half(w0[(size_t)s * 8192 + c * 16 + tap]));
    }
    float sq = 0.f;
    for (int i = tid; i < 8192; i += 256) {
      float v = w0[(size_t)s * 8192 + i];
      wmaster[(size_t)s * 8192 + i] = v;
      sq += v * v;
    }
    sq = waveSum(sq);
    if ((tid & 63) == 0) sred[tid >> 6] = sq;
    __syncthreads();
    if (tid == 0) part[P_WSQ0 + s] = sred[0] + sred[1] + sred[2] + sred[3];
  } else {
    int p = (b - 1568) * 256 + tid;
    if (p < NP) {
      int nsid = p / P2, rem = p % P2;
      int i = rem / OH, j = rem % OH;
      const float* bp = bb + (size_t)nsid * 4;
      float cr = (bp[1] + 0.5f * bp[3]) * 0.0625f;
      float cc = (bp[0] + 0.5f * bp[2]) * 0.0625f;
      float dy = (float)i - cr, dx = (float)j - cc;
      label[p] = __expf(-0.5f * (dy * dy + dx * dx));
    }
  }
}

// ---------------- forward conv via MFMA, K(channel)-split ----------------
// Per (s,n,ch): partial G[uv,tap] over 256 channels (8-step MFMA chain, no halo),
// then partial scores gather -> outA (ch=0) / outB (ch=1). Merge in consumers.
// grid = 96 snT x 2 ch = 192 blocks x 1024 (16 waves; wave w owns M-tiles w, w+16).
__global__ __launch_bounds__(1024) void k_conv_fwd(const u16* __restrict__ featT,
                                                   const u16* __restrict__ wf16,
                                                   float* __restrict__ outA,
                                                   float* __restrict__ outB) {
  __shared__ uint32 w_lds[16 * 132];  // [tap][c-pair of this half], pitch 132
  __shared__ float G[496 * 17];       // [uv-row][tap], 31 tiles
  int tid = threadIdx.x;
  int bidx = blockIdx.x;
  int snT = bidx >> 1, ch = bidx & 1;
  int s = snT / 3, n = snT - s * 3;
  const uint32* wsrc = (const uint32*)(wf16 + (size_t)s * 8192) + ch * 128;
  for (int i = tid; i < 2048; i += 1024) {
    int tap = i >> 7, p = i & 127;
    w_lds[tap * 132 + p] = wsrc[(size_t)tap * 256 + p];
  }
  __syncthreads();
  int wave = tid >> 6, lane = tid & 63;
  int q = lane >> 4, m16 = lane & 15;
  int t0 = wave, t1 = wave + 16;
  bool has2 = (t1 < 31);
  f32x4 acc0 = {0.f, 0.f, 0.f, 0.f}, acc1 = {0.f, 0.f, 0.f, 0.f};
  size_t base = (size_t)snT * 4 * UV * 128;
  int r0i = t0 * 16 + m16;                 // <= 255
  int r1i = has2 ? t1 * 16 + m16 : 483;
  if (r1i > 483) r1i = 483;                // tile 30 pad rows: clamp (never gathered)
  size_t row0 = (size_t)r0i * 128;
  size_t row1 = (size_t)r1i * 128;
#pragma unroll
  for (int ks = 0; ks < 8; ++ks) {
    int cb = ch * 2 + (ks >> 2), cin = (ks & 3) * 32;
    size_t cbase = base + (size_t)cb * UV * 128 + cin + q * 8;
    f16x8 a0 = *(const f16x8*)(featT + cbase + row0);
    uint4 bw = *(const uint4*)&w_lds[m16 * 132 + ks * 16 + q * 4];
    f16x8 bf = __builtin_bit_cast(f16x8, bw);
    acc0 = __builtin_amdgcn_mfma_f32_16x16x32_f16(a0, bf, acc0, 0, 0, 0);
    if (has2) {
      f16x8 a1 = *(const f16x8*)(featT + cbase + row1);
      acc1 = __builtin_amdgcn_mfma_f32_16x16x32_f16(a1, bf, acc1, 0, 0, 0);
    }
  }
  // D layout: col=lane&15 (tap), row=(lane>>4)*4+reg (uv within tile)
#pragma unroll
  for (int r = 0; r < 4; ++r) G[(t0 * 16 + q * 4 + r) * 17 + m16] = acc0[r];
  if (has2) {
#pragma unroll
    for (int r = 0; r < 4; ++r) G[(t1 * 16 + q * 4 + r) * 17 + m16] = acc1[r];
  }
  __syncthreads();
  if (tid < P2) {
    int y = tid / 23, x = tid - y * 23;
    float val = 0.f;
#pragma unroll
    for (int ky = 0; ky < 4; ++ky) {
      int u = y + ky - 2;
      if ((unsigned)u < 22u) {
#pragma unroll
        for (int kx = 0; kx < 4; ++kx) {
          int v = x + kx - 2;
          if ((unsigned)v < 22u) val += G[(u * 22 + v) * 17 + ky * 4 + kx];
        }
      }
    }
    float* dst = ch ? outB : outA;
    dst[(size_t)(n * NS + s) * P2 + tid] = val;
  }
}

// ---------------- adjoint via MFMA + fused alpha/w-update/scores-recurrence/loss -----
// Per (s, chunk of 64 c): D[c,tap] = sum_k A[c,k] * Rs[tap,k], K=1536.
// t==0: A from feat (f32->f16 in-register), writes k-blocked featC as byproduct.
// t>=1: A from k-blocked featC, fully coalesced.
// g = sga+sgb cached in LDS by phase 0 (same-thread reuse in phase 1 — no extra sync).
// grid = 32 s * 8 chunks = 256 blocks x 1024 (16 waves: tile=wave&3, kq=wave>>2).
__global__ __launch_bounds__(1024) void k_adjoint(
    int t, const float* __restrict__ feat, u16* __restrict__ featC,
    const float* __restrict__ label, const float* __restrict__ s0a,
    const float* __restrict__ s0b, const float* __restrict__ scores_old,
    float* __restrict__ scores_new, const float* __restrict__ sga,
    const float* __restrict__ sgb, float* __restrict__ wg, u16* __restrict__ wgf16,
    float* __restrict__ wmaster, float* __restrict__ part, const float* __restrict__ lsl,
    const float* __restrict__ fr) {
  __shared__ float r_lds[3 * P2];              // rm = sw^2 * resid, [n][y*23+x]
  __shared__ float g_lds[1587];                // sga+sgb cache (phase0 -> phase1)
  __shared__ __align__(16) u16 rs[16 * RSP];   // [tap][k], pitch RSP halves
  __shared__ __align__(16) float kred[3 * 4 * 64 * 4];
  __shared__ float lred[16], nred[16], wred[16], dend[16];
  int tid = threadIdx.x;
  int s = blockIdx.x >> 3, chunk = blockIdx.x & 7;
  int c0 = chunk * 64;
  float step = __expf(lsl[0]);
  float frv = fr[0];
  float reg = fmaxf(frv * frv, 1e-6f);

  // ---- phase 0: alpha_{t-1} from P_NUM + block-local sum of (sga+sgb)^2 ----
  float alpha_p = 0.f;
  if (t >= 1) {
    const float* np_ = part + P_NUM + (size_t)((t - 1) * NS + s) * 8;
    float nu = 0.f;
#pragma unroll
    for (int i = 0; i < 8; ++i) nu += np_[i];
    float dp = 0.f;
    for (int pl = tid; pl < 1587; pl += 1024) {
      int nn = (unsigned)pl / (unsigned)P2;
      int rem = pl - nn * P2;
      size_t gp = (size_t)(nn * NS + s) * P2 + rem;
      float g = sga[gp] + sgb[gp];
      g_lds[pl] = g;
      dp += g * g;
    }
    dp = waveSum(dp);
    if ((tid & 63) == 0) dend[tid >> 6] = dp;
    __syncthreads();
    float de = 0.f;
#pragma unroll
    for (int i = 0; i < 16; ++i) de += dend[i];
    alpha_p = nu / fmaxf(de * (1.0f / 3.0f) + reg * nu, 1e-8f);
  }

  // ---- phase 1: residuals (+ scores recurrence, loss on chunk 0) ----
  float lsum = 0.f;
  for (int pl = tid; pl < 1587; pl += 1024) {
    int nn = (unsigned)pl / (unsigned)P2;
    int rem = pl - nn * P2;
    size_t gp = (size_t)(nn * NS + s) * P2 + rem;
    float S = (t <= 1) ? (s0a[gp] + s0b[gp]) : scores_old[gp];
    if (t >= 1) S -= step * alpha_p * g_lds[pl];
    float d = S - label[gp];
    r_lds[nn * P2 + rem] = d * (1.0f / 3.0f);
    if (chunk == 0) {
      if (t >= 1) scores_new[gp] = S;
      lsum += d * d;
    }
  }
  lsum = waveSum(lsum);
  if ((tid & 63) == 0) lred[tid >> 6] = lsum;
  __syncthreads();
  if (chunk == 0 && tid == 0) {
    float L = 0.f;
#pragma unroll
    for (int i = 0; i < 16; ++i) L += lred[i];
    part[P_LOSS + t * NS + s] = L * (1.0f / 3.0f);
  }

  // ---- phase 2: build Rs [tap][k] f16 in LDS ----
  for (int idx = tid; idx < 16 * RSP; idx += 1024) {
    int tap = (unsigned)idx / (unsigned)RSP;
    int k = idx - tap * RSP;
    float val = 0.f;
    if (k < KTOT) {
      int n = k >> 9, uv = k & 511;
      if (uv < UV) {
        int u = (unsigned)uv / 22u;
        int v = uv - u * 22;
        int ky = tap >> 2, kx = tap & 3;
        int y = u + 2 - ky, x = v + 2 - kx;
        if ((unsigned)y < 23u && (unsigned)x < 23u) val = r_lds[n * P2 + y * OH + x];
      }
    }
    rs[idx] = __half_as_ushort(__float2half(val));
  }
  __syncthreads();

  // ---- phase 3: MFMA GEMM, 4 M-tiles x 4 K-quarters (12 K-steps each) ----
  int wave = tid >> 6, lane = tid & 63;
  int q = lane >> 4, m16 = lane & 15;
  int tile = wave & 3, kq = wave >> 2;
  int c = c0 + tile * 16 + m16;
  const u16* brow = rs + m16 * RSP + kq * 384 + q * 8;
  f32x4 acc = {0.f, 0.f, 0.f, 0.f};
  if (t == 0) {
#pragma unroll
    for (int ks = 0; ks < 12; ++ks) {
      int kb = kq * 12 + ks;
      int k0 = kb * 32 + q * 8;
      int nn = k0 >> 9, uv0 = k0 & 511;
      float v[8];
#pragma unroll
      for (int i = 0; i < 8; ++i) v[i] = 0.f;
      if (uv0 < UV) {
        const float* fsrc = feat + ((size_t)(nn * NS + s) * CHN + c) * UV + uv0;
        if (uv0 + 8 <= UV) {
          float4 p0 = *(const float4*)fsrc;
          float4 p1 = *(const float4*)(fsrc + 4);
          v[0] = p0.x; v[1] = p0.y; v[2] = p0.z; v[3] = p0.w;
          v[4] = p1.x; v[5] = p1.y; v[6] = p1.z; v[7] = p1.w;
        } else {  // uv0 == 480: 4 valid
#pragma unroll
          for (int i = 0; i < 4; ++i) v[i] = fsrc[i];
        }
      }
      union { u16 h[8]; f16x8 f; uint4 u; } av;
#pragma unroll
      for (int i = 0; i < 8; ++i) av.h[i] = __half_as_ushort(__float2half(v[i]));
      *(uint4*)(featC + (((size_t)(s * NKB + kb) * CHN + c) * 32 + q * 8)) = av.u;
      f16x8 bf = *(const f16x8*)(brow + ks * 32);
      acc = __builtin_amdgcn_mfma_f32_16x16x32_f16(av.f, bf, acc, 0, 0, 0);
    }
  } else {
    const u16* arow = featC + ((size_t)(s * NKB + kq * 12) * CHN + c) * 32 + q * 8;
#pragma unroll
    for (int ks = 0; ks < 12; ++ks) {
      f16x8 a = *(const f16x8*)(arow + (size_t)ks * (CHN * 32));
      f16x8 bf = *(const f16x8*)(brow + ks * 32);
      acc = __builtin_amdgcn_mfma_f32_16x16x32_f16(a, bf, acc, 0, 0, 0);
    }
  }
  if (kq) *(f32x4*)&kred[(((kq - 1) * 4 + tile) * 64 + lane) * 4] = acc;
  __syncthreads();

  // ---- phase 4: epilogue (kq==0 waves): w update, wg/wgf16 write, partials ----
  float num_part = 0.f, wsq_part = 0.f;
  if (kq == 0) {
#pragma unroll
    for (int kk = 0; kk < 3; ++kk)
      acc += *(const f32x4*)&kred[((kk * 4 + tile) * 64 + lane) * 4];
    int tap = m16;
    int ccb = c0 + tile * 16 + q * 4;  // base c of this lane's 4 rows
    union { u16 h[4]; uint2 v2; } pk;
#pragma unroll
    for (int r = 0; r < 4; ++r) {
      int cc = ccb + r;
      size_t widx = (size_t)s * 8192 + (size_t)cc * 16 + tap;
      float wold = wmaster[widx];
      float wnew = wold;
      if (t >= 1) {
        wnew = wold - step * alpha_p * wg[widx];
        wmaster[widx] = wnew;
      }
      float wgn = acc[r] + reg * wnew;
      wg[widx] = wgn;
      pk.h[r] = __half_as_ushort(__float2half(wgn));
      wsq_part += wnew * wnew;
      num_part += wgn * wgn;
    }
    *(uint2*)&wgf16[(size_t)s * 8192 + (size_t)tap * 512 + ccb] = pk.v2;
  }
  num_part = waveSum(num_part);
  wsq_part = waveSum(wsq_part);
  if (lane == 0) {
    nred[wave] = num_part;
    wred[wave] = wsq_part;
  }
  __syncthreads();
  if (tid == 0) {
    float nsum = 0.f, wsum = 0.f;
#pragma unroll
    for (int i = 0; i < 16; ++i) {
      nsum += nred[i];
      wsum += wred[i];
    }
    part[P_NUM + (size_t)(t * NS + s) * 8 + chunk] = nsum;
    if (t >= 1) part[P_WSQA + (size_t)((t - 1) * NS + s) * 8 + chunk] = wsum;
  }
}

// ---------------- block-local alpha4: nu from P_NUM, den summed from sgraw ----------
__device__ __forceinline__ float blockAlpha(int s, const float* __restrict__ sga,
                                            const float* __restrict__ sgb,
                                            const float* __restrict__ part, float reg,
                                            int tid, float* ared) {
  float dp = 0.f;
  for (int pl = tid; pl < 1587; pl += 256) {
    int nn = (unsigned)pl / (unsigned)P2;
    int rem = pl - nn * P2;
    size_t gp = (size_t)(nn * NS + s) * P2 + rem;
    float g = sga[gp] + sgb[gp];
    dp += g * g;
  }
  dp = waveSum(dp);
  __syncthreads();
  if ((tid & 63) == 0) ared[tid >> 6] = dp;
  __syncthreads();
  float de = (ared[0] + ared[1] + ared[2] + ared[3]) * (1.0f / 3.0f);
  const float* np_ = part + P_NUM + (size_t)(4 * NS + s) * 8;
  float nu = 0.f;
#pragma unroll
  for (int i = 0; i < 8; ++i) nu += np_[i];
  return nu / fmaxf(de + reg * nu, 1e-8f);
}

// ---------------- final: w5 update + final loss parts + ticketed losses fold --------
// grid = 1223 blocks x 256. Last block (atomic ticket) sums all partials -> losses.
__global__ __launch_bounds__(256) void k_final(
    float* __restrict__ wmaster, const float* __restrict__ wg,
    const float* __restrict__ scores4, const float* __restrict__ sga,
    const float* __restrict__ sgb, const float* __restrict__ label,
    float* __restrict__ part, const float* __restrict__ lsl,
    const float* __restrict__ fr, float* __restrict__ out_losses) {
  __shared__ float aredS[4];
  __shared__ float red4[4];
  __shared__ uint32 tkt_s;
  int b = blockIdx.x, tid = threadIdx.x;
  float step = __expf(lsl[0]);
  float frv = fr[0];
  float reg = fmaxf(frv * frv, 1e-6f);
  if (b < 1024) {
    int s = b >> 5;  // 32 blocks per s (8192 w-elems / 256)
    float alpha = blockAlpha(s, sga, sgb, part, reg, tid, aredS);
    int idx = b * 256 + tid;  // 1024*256 == 262144 exactly
    float w5 = wmaster[idx] - step * alpha * wg[idx];
    wmaster[idx] = w5;
    float sq = waveSum(w5 * w5);
    __syncthreads();
    if ((tid & 63) == 0) red4[tid >> 6] = sq;
    __syncthreads();
    if (tid == 0) part[P_WSQ5 + b] = red4[0] + red4[1] + red4[2] + red4[3];
  } else {
    int p0 = (b - 1024) * 256;
    int nsid0 = (unsigned)p0 / (unsigned)P2;
    int plast = p0 + 255;
    if (plast > NP - 1) plast = NP - 1;
    int nsid1 = (unsigned)plast / (unsigned)P2;
    float alphaA = blockAlpha(nsid0 & 31, sga, sgb, part, reg, tid, aredS);
    float alphaB = alphaA;
    if (nsid1 != nsid0) alphaB = blockAlpha(nsid1 & 31, sga, sgb, part, reg, tid, aredS);
    int p = p0 + tid;
    float contrib = 0.f;
    if (p < NP) {
      int nsid = (unsigned)p / (unsigned)P2;
      float alpha = (nsid == nsid0) ? alphaA : alphaB;
      float s5 = scores4[p] - step * alpha * (sga[p] + sgb[p]);
      float d = s5 - label[p];
      contrib = d * d;
    }
    contrib = waveSum(contrib);
    __syncthreads();
    if ((tid & 63) == 0) red4[tid >> 6] = contrib;
    __syncthreads();
    if (tid == 0)
      part[P_L5 + (b - 1024)] = (red4[0] + red4[1] + red4[2] + red4[3]) * (1.0f / 3.0f);
  }
  // ---- ticket: last block deterministically sums all partials into losses ----
  __threadfence();  // release this block's partial store (tid0 program order)
  __syncthreads();
  if (tid == 0) tkt_s = atomicAdd((uint32*)&part[P_TICKET], 1u);
  __syncthreads();
  if (tkt_s == 1222) {
    __threadfence();  // acquire: all 1222 prior blocks' stores now visible
    float v5 = 0.f;
    for (int i = tid; i < 1024; i += 256) v5 += part[P_WSQ5 + i];
    v5 = waveSum(v5);
    if ((tid & 63) == 0) red4[tid >> 6] = v5;
    __syncthreads();
    float wsq5 = red4[0] + red4[1] + red4[2] + red4[3];
    float l5 = 0.f;
    for (int i = tid; i < 199; i += 256) l5 += part[P_L5 + i];
    l5 = waveSum(l5);
    if ((tid & 63) == 0) aredS[tid >> 6] = l5;
    __syncthreads();
    float loss5 = aredS[0] + aredS[1] + aredS[2] + aredS[3];
    if (tid < 5) {
      int t = tid;
      float ls = 0.f;
      for (int i = 0; i < 32; ++i) ls += part[P_LOSS + t * NS + i];
      float ws_ = 0.f;
      if (t == 0) {
        for (int i = 0; i < 32; ++i) ws_ += part[P_WSQ0 + i];
      } else {
        for (int i = 0; i < 256; ++i) ws_ += part[P_WSQA + (t - 1) * 256 + i];
      }
      out_losses[t] = (ls + reg * ws_) * (1.0f / 32.0f);
    }
    if (tid == 5) out_losses[5] = (loss5 + reg * wsq5) * (1.0f / 32.0f);
  }
}

// ---------------- launch ----------------
extern "C" void kernel_launch(void* const* d_in, const int* in_sizes, int n_in,
                              void* d_out, int out_size, void* d_ws, size_t ws_size,
                              hipStream_t stream) {
  const float* w0 = (const float*)d_in[0];
  const float* feat = (const float*)d_in[1];
  const float* bb = (const float*)d_in[2];
  const float* lsl = (const float*)d_in[3];
  const float* fr = (const float*)d_in[4];
  float* out = (float*)d_out;
  char* ws = (char*)d_ws;
  u16* featT = (u16*)(ws + OFF_FEATT);
  float* label = (float*)(ws + OFF_LABEL);
  float* s0 = (float*)(ws + OFF_S0);
  float* s0b = (float*)(ws + OFF_S0B);
  float* s1 = (float*)(ws + OFF_S1);
  float* sga = (float*)(ws + OFF_SGRAW);
  float* sgb = (float*)(ws + OFF_SGB);
  float* wg = (float*)(ws + OFF_WG);
  u16* wgf16 = (u16*)(ws + OFF_WGF16);
  u16* w0f16 = (u16*)(ws + OFF_W0F16);
  float* part = (float*)(ws + OFF_PART);
  u16* featC = (u16*)(ws + OFF_FEATC);

  k_setup<<<1767, 256, 0, stream>>>(feat, w0, bb, featT, w0f16, out, label, part);
  // initial scores_0 partials = A * w0  (A half / B half)
  k_conv_fwd<<<192, 1024, 0, stream>>>(featT, w0f16, s0, s0b);
  // merged scores ping-pong: t=1 writes s1, t=2 writes s0 (s0a dead after t=1), ...
  for (int t = 0; t < 5; ++t) {
    const float* so = (t <= 1) ? s0 : ((t & 1) ? s0 : s1);  // t=2,4 read s1; t=3 reads s0
    float* sn = (t & 1) ? s1 : s0;                          // t=1->s1, t=2->s0, ...
    k_adjoint<<<256, 1024, 0, stream>>>(t, feat, featC, label, s0, s0b, so, sn, sga, sgb,
                                        wg, wgf16, out, part, lsl, fr);
    k_conv_fwd<<<192, 1024, 0, stream>>>(featT, wgf16, sga, sgb);
  }
  // merged scores_4 lives in s0 (t=4 wrote sn=s0); sgraw4 partials in sga/sgb
  k_final<<<1223, 256, 0, stream>>>(out, wg, s0, sga, sgb, label, part, lsl, fr,
                                    out + WSZ);
}

// Round 12
// 360.099 us; speedup vs baseline: 1.2086x; 1.2086x over previous
//
#include <hip/hip_runtime.h>
#include <hip/hip_fp16.h>

// ---------------- problem constants ----------------
#define NI 3
#define NS 32
#define CHN 512
#define OH 23
#define P2 529          // 23*23
#define NP 50784        // NI*NS*P2
#define UV 484          // 22*22
#define WSZ 262144      // NS*CHN*16
#define KTOT 1536       // 3n * 512 (uv padded 484->512)
#define NKB 48          // KTOT/32 k-blocks
#define RSP 1544        // Rs LDS pitch in halves (16B-aligned rows, bank-stagger)

typedef unsigned int uint32;
typedef unsigned short u16;
typedef _Float16 h2 __attribute__((ext_vector_type(2)));
typedef _Float16 f16x8 __attribute__((ext_vector_type(8)));
typedef float f32x4 __attribute__((ext_vector_type(4)));

// ---------------- workspace layout (bytes) ----------------
// featT layout: [snT(96)][cb4(4)][uv(484)][c(128)] f16, snT = s*3+n
// featC layout (k-blocked): [s(32)][kb(48)][c(512)][32] f16, k = kb*32+kk = n*512+uv
//   (uv 484..511 zero). Written by k_adjoint t=0 as a byproduct; read t>=1.
#define OFF_FEATT 0UL           // 23,789,568 halves = 47,579,136 B
#define OFF_LABEL 47579136UL    // 50784 f32
#define OFF_S0    47782272UL    // 50784 f32 (scores partial A / merged ping)
#define OFF_S1    47985408UL    // 50784 f32 (merged pong)
#define OFF_SGRAW 48188544UL    // 50784 f32 (A*wg raw, partial A)
#define OFF_WG    48391680UL    // 262144 f32
#define OFF_WGF16 49440256UL    // 262144 f16, layout [s][tap][c]
#define OFF_W0F16 49964544UL    // 262144 f16, layout [s][tap][c]
#define OFF_PART  50488832UL    // partial-sum arrays (float), ~32 KB
#define OFF_FEATC 50521600UL    // 32*48*512*32 f16 = 50,331,648 B
#define OFF_S0B   100853248UL   // 50784 f32 (scores partial B)
#define OFF_SGB   101056384UL   // 50784 f32 (A*wg raw, partial B)

// partial-array float indices — each slot written by exactly ONE block; NO atomics.
#define P_DEN   0       // [32] : per-s sum sgraw4^2 /3 (written by k_den)
#define P_NUM   4320    // [5][32][8]  : per-(t,s,chunk) sum wg^2 partials
#define P_LOSS  5600    // [5][32]     : per-(t,s) residual-loss partials
#define P_WSQ0  5760    // [32]        : sum w0^2 per s
#define P_WSQA  5792    // [4][32][8]  : sum w_t^2 partials, t=1..4
#define P_WSQ5  6816    // [1024]      : sum w5^2 per block
#define P_L5    7840    // [199]       : final loss per block

__device__ __forceinline__ float waveSum(float v) {
#pragma unroll
  for (int o = 32; o > 0; o >>= 1) v += __shfl_xor(v, o, 64);
  return v;
}

// ---------------- setup: feat->f16 transpose to featT, + w, label --------------------
// transpose tile = (snT, cb of 64 ch, uvh of 242 uv): LDS [64 c][121 u32-pairs] = 31 KB
// grid = 1536 (tiles) + 32 (w) + 199 (label) = 1767 blocks x 256
__global__ __launch_bounds__(256) void k_setup(const float* __restrict__ feat,
                                               const float* __restrict__ w0,
                                               const float* __restrict__ bb,
                                               u16* __restrict__ featT,
                                               u16* __restrict__ w0f16,
                                               float* __restrict__ wmaster,
                                               float* __restrict__ label,
                                               float* __restrict__ part) {
  __shared__ uint32 lds32[64 * 121];  // [64 c][242 uv] f16 as u32 pairs, pitch 121
  __shared__ float sred[4];
  int b = blockIdx.x, tid = threadIdx.x;
  if (b < 1536) {
    int snT = b >> 4, r4 = b & 15;
    int cb = r4 >> 1, uvh = r4 & 1;  // 64-ch group, 242-uv half
    int s = snT / 3, n = snT % 3;
    const float* fsrc =
        feat + ((size_t)n * NS + s) * CHN * UV + (size_t)(cb * 64) * UV + uvh * 242;
#pragma unroll
    for (int it = 0; it < 31; ++it) {
      int idx = it * 256 + tid;
      if (idx < 7744) {
        int r = (unsigned)idx / 121u;
        int j = idx - r * 121;
        float2 v = *(const float2*)(fsrc + (size_t)r * UV + 2 * j);
        lds32[idx] = (uint32)__half_as_ushort(__float2half(v.x)) |
                     ((uint32)__half_as_ushort(__float2half(v.y)) << 16);
      }
    }
    __syncthreads();
    uint32* dstT = (uint32*)featT +
                   ((size_t)(snT * 4 + (cb >> 1)) * UV + uvh * 242) * 64 + (cb & 1) * 32;
#pragma unroll
    for (int it = 0; it < 16; ++it) {
      int o = it * 256 + tid;
      if (o < 3872) {
        int uv = o >> 4, kp = o & 15;
        int j = uv >> 1, sh = (uv & 1) * 16;
        uint32 a0 = lds32[(4 * kp + 0) * 121 + j];
        uint32 a1 = lds32[(4 * kp + 1) * 121 + j];
        uint32 a2 = lds32[(4 * kp + 2) * 121 + j];
        uint32 a3 = lds32[(4 * kp + 3) * 121 + j];
        uint2 val;
        val.x = ((a0 >> sh) & 0xffffu) | (((a1 >> sh) & 0xffffu) << 16);
        val.y = ((a2 >> sh) & 0xffffu) | (((a3 >> sh) & 0xffffu) << 16);
        *(uint2*)(dstT + (size_t)uv * 64 + 2 * kp) = val;
      }
    }
  } else if (b < 1568) {
    int s = b - 1536;
    for (int i = tid; i < 8192; i += 256) {
      int tap = i >> 9, c = i & 511;
      w0f16[(size_t)s * 8192 + i] =
          __half_as_ushort(__float2half(w0[(size_t)s * 8192 + c * 16 + tap]));
    }
    float sq = 0.f;
    for (int i = tid; i < 8192; i += 256) {
      float v = w0[(size_t)s * 8192 + i];
      wmaster[(size_t)s * 8192 + i] = v;
      sq += v * v;
    }
    sq = waveSum(sq);
    if ((tid & 63) == 0) sred[tid >> 6] = sq;
    __syncthreads();
    if (tid == 0) part[P_WSQ0 + s] = sred[0] + sred[1] + sred[2] + sred[3];
  } else {
    int p = (b - 1568) * 256 + tid;
    if (p < NP) {
      int nsid = p / P2, rem = p % P2;
      int i = rem / OH, j = rem % OH;
      const float* bp = bb + (size_t)nsid * 4;
      float cr = (bp[1] + 0.5f * bp[3]) * 0.0625f;
      float cc = (bp[0] + 0.5f * bp[2]) * 0.0625f;
      float dy = (float)i - cr, dx = (float)j - cc;
      label[p] = __expf(-0.5f * (dy * dy + dx * dx));
    }
  }
}

// ---------------- forward conv via MFMA, K(channel)-split ----------------
// Per (s,n,ch): partial G[uv,tap] over 256 channels (8-step MFMA chain, no halo),
// then partial scores gather -> outA (ch=0) / outB (ch=1). Merge in consumers.
// grid = 96 snT x 2 ch = 192 blocks x 1024 (16 waves; wave w owns M-tiles w, w+16).
__global__ __launch_bounds__(1024) void k_conv_fwd(const u16* __restrict__ featT,
                                                   const u16* __restrict__ wf16,
                                                   float* __restrict__ outA,
                                                   float* __restrict__ outB) {
  __shared__ uint32 w_lds[16 * 132];  // [tap][c-pair of this half], pitch 132
  __shared__ float G[496 * 17];       // [uv-row][tap], 31 tiles
  int tid = threadIdx.x;
  int bidx = blockIdx.x;
  int snT = bidx >> 1, ch = bidx & 1;
  int s = snT / 3, n = snT - s * 3;
  const uint32* wsrc = (const uint32*)(wf16 + (size_t)s * 8192) + ch * 128;
  for (int i = tid; i < 2048; i += 1024) {
    int tap = i >> 7, p = i & 127;
    w_lds[tap * 132 + p] = wsrc[(size_t)tap * 256 + p];
  }
  __syncthreads();
  int wave = tid >> 6, lane = tid & 63;
  int q = lane >> 4, m16 = lane & 15;
  int t0 = wave, t1 = wave + 16;
  bool has2 = (t1 < 31);
  f32x4 acc0 = {0.f, 0.f, 0.f, 0.f}, acc1 = {0.f, 0.f, 0.f, 0.f};
  size_t base = (size_t)snT * 4 * UV * 128;
  int r0i = t0 * 16 + m16;                 // <= 255
  int r1i = has2 ? t1 * 16 + m16 : 483;
  if (r1i > 483) r1i = 483;                // tile 30 pad rows: clamp (never gathered)
  size_t row0 = (size_t)r0i * 128;
  size_t row1 = (size_t)r1i * 128;
#pragma unroll
  for (int ks = 0; ks < 8; ++ks) {
    int cb = ch * 2 + (ks >> 2), cin = (ks & 3) * 32;
    size_t cbase = base + (size_t)cb * UV * 128 + cin + q * 8;
    f16x8 a0 = *(const f16x8*)(featT + cbase + row0);
    uint4 bw = *(const uint4*)&w_lds[m16 * 132 + ks * 16 + q * 4];
    f16x8 bf = __builtin_bit_cast(f16x8, bw);
    acc0 = __builtin_amdgcn_mfma_f32_16x16x32_f16(a0, bf, acc0, 0, 0, 0);
    if (has2) {
      f16x8 a1 = *(const f16x8*)(featT + cbase + row1);
      acc1 = __builtin_amdgcn_mfma_f32_16x16x32_f16(a1, bf, acc1, 0, 0, 0);
    }
  }
  // D layout: col=lane&15 (tap), row=(lane>>4)*4+reg (uv within tile)
#pragma unroll
  for (int r = 0; r < 4; ++r) G[(t0 * 16 + q * 4 + r) * 17 + m16] = acc0[r];
  if (has2) {
#pragma unroll
    for (int r = 0; r < 4; ++r) G[(t1 * 16 + q * 4 + r) * 17 + m16] = acc1[r];
  }
  __syncthreads();
  if (tid < P2) {
    int y = tid / 23, x = tid - y * 23;
    float val = 0.f;
#pragma unroll
    for (int ky = 0; ky < 4; ++ky) {
      int u = y + ky - 2;
      if ((unsigned)u < 22u) {
#pragma unroll
        for (int kx = 0; kx < 4; ++kx) {
          int v = x + kx - 2;
          if ((unsigned)v < 22u) val += G[(u * 22 + v) * 17 + ky * 4 + kx];
        }
      }
    }
    float* dst = ch ? outB : outA;
    dst[(size_t)(n * NS + s) * P2 + tid] = val;
  }
}

// ---------------- adjoint via MFMA + fused alpha/w-update/scores-recurrence/loss -----
// Per (s, chunk of 64 c): D[c,tap] = sum_k A[c,k] * Rs[tap,k], K=1536.
// t==0: A from feat (f32->f16 in-register), writes k-blocked featC as byproduct.
// t>=1: A from k-blocked featC, fully coalesced.
// g = sga+sgb cached in LDS by phase 0 (same-thread reuse in phase 1 — no extra sync).
// grid = 32 s * 8 chunks = 256 blocks x 1024 (16 waves: tile=wave&3, kq=wave>>2).
__global__ __launch_bounds__(1024) void k_adjoint(
    int t, const float* __restrict__ feat, u16* __restrict__ featC,
    const float* __restrict__ label, const float* __restrict__ s0a,
    const float* __restrict__ s0b, const float* __restrict__ scores_old,
    float* __restrict__ scores_new, const float* __restrict__ sga,
    const float* __restrict__ sgb, float* __restrict__ wg, u16* __restrict__ wgf16,
    float* __restrict__ wmaster, float* __restrict__ part, const float* __restrict__ lsl,
    const float* __restrict__ fr) {
  __shared__ float r_lds[3 * P2];              // rm = sw^2 * resid, [n][y*23+x]
  __shared__ float g_lds[1587];                // sga+sgb cache (phase0 -> phase1)
  __shared__ __align__(16) u16 rs[16 * RSP];   // [tap][k], pitch RSP halves
  __shared__ __align__(16) float kred[3 * 4 * 64 * 4];
  __shared__ float lred[16], nred[16], wred[16], dend[16];
  int tid = threadIdx.x;
  int s = blockIdx.x >> 3, chunk = blockIdx.x & 7;
  int c0 = chunk * 64;
  float step = __expf(lsl[0]);
  float frv = fr[0];
  float reg = fmaxf(frv * frv, 1e-6f);

  // ---- phase 0: alpha_{t-1} from P_NUM + block-local sum of (sga+sgb)^2 ----
  float alpha_p = 0.f;
  if (t >= 1) {
    const float* np_ = part + P_NUM + (size_t)((t - 1) * NS + s) * 8;
    float nu = 0.f;
#pragma unroll
    for (int i = 0; i < 8; ++i) nu += np_[i];
    float dp = 0.f;
    for (int pl = tid; pl < 1587; pl += 1024) {
      int nn = (unsigned)pl / (unsigned)P2;
      int rem = pl - nn * P2;
      size_t gp = (size_t)(nn * NS + s) * P2 + rem;
      float g = sga[gp] + sgb[gp];
      g_lds[pl] = g;
      dp += g * g;
    }
    dp = waveSum(dp);
    if ((tid & 63) == 0) dend[tid >> 6] = dp;
    __syncthreads();
    float de = 0.f;
#pragma unroll
    for (int i = 0; i < 16; ++i) de += dend[i];
    alpha_p = nu / fmaxf(de * (1.0f / 3.0f) + reg * nu, 1e-8f);
  }

  // ---- phase 1: residuals (+ scores recurrence, loss on chunk 0) ----
  float lsum = 0.f;
  for (int pl = tid; pl < 1587; pl += 1024) {
    int nn = (unsigned)pl / (unsigned)P2;
    int rem = pl - nn * P2;
    size_t gp = (size_t)(nn * NS + s) * P2 + rem;
    float S = (t <= 1) ? (s0a[gp] + s0b[gp]) : scores_old[gp];
    if (t >= 1) S -= step * alpha_p * g_lds[pl];
    float d = S - label[gp];
    r_lds[nn * P2 + rem] = d * (1.0f / 3.0f);
    if (chunk == 0) {
      if (t >= 1) scores_new[gp] = S;
      lsum += d * d;
    }
  }
  lsum = waveSum(lsum);
  if ((tid & 63) == 0) lred[tid >> 6] = lsum;
  __syncthreads();
  if (chunk == 0 && tid == 0) {
    float L = 0.f;
#pragma unroll
    for (int i = 0; i < 16; ++i) L += lred[i];
    part[P_LOSS + t * NS + s] = L * (1.0f / 3.0f);
  }

  // ---- phase 2: build Rs [tap][k] f16 in LDS ----
  for (int idx = tid; idx < 16 * RSP; idx += 1024) {
    int tap = (unsigned)idx / (unsigned)RSP;
    int k = idx - tap * RSP;
    float val = 0.f;
    if (k < KTOT) {
      int n = k >> 9, uv = k & 511;
      if (uv < UV) {
        int u = (unsigned)uv / 22u;
        int v = uv - u * 22;
        int ky = tap >> 2, kx = tap & 3;
        int y = u + 2 - ky, x = v + 2 - kx;
        if ((unsigned)y < 23u && (unsigned)x < 23u) val = r_lds[n * P2 + y * OH + x];
      }
    }
    rs[idx] = __half_as_ushort(__float2half(val));
  }
  __syncthreads();

  // ---- phase 3: MFMA GEMM, 4 M-tiles x 4 K-quarters (12 K-steps each) ----
  int wave = tid >> 6, lane = tid & 63;
  int q = lane >> 4, m16 = lane & 15;
  int tile = wave & 3, kq = wave >> 2;
  int c = c0 + tile * 16 + m16;
  const u16* brow = rs + m16 * RSP + kq * 384 + q * 8;
  f32x4 acc = {0.f, 0.f, 0.f, 0.f};
  if (t == 0) {
#pragma unroll
    for (int ks = 0; ks < 12; ++ks) {
      int kb = kq * 12 + ks;
      int k0 = kb * 32 + q * 8;
      int nn = k0 >> 9, uv0 = k0 & 511;
      float v[8];
#pragma unroll
      for (int i = 0; i < 8; ++i) v[i] = 0.f;
      if (uv0 < UV) {
        const float* fsrc = feat + ((size_t)(nn * NS + s) * CHN + c) * UV + uv0;
        if (uv0 + 8 <= UV) {
          float4 p0 = *(const float4*)fsrc;
          float4 p1 = *(const float4*)(fsrc + 4);
          v[0] = p0.x; v[1] = p0.y; v[2] = p0.z; v[3] = p0.w;
          v[4] = p1.x; v[5] = p1.y; v[6] = p1.z; v[7] = p1.w;
        } else {  // uv0 == 480: 4 valid
#pragma unroll
          for (int i = 0; i < 4; ++i) v[i] = fsrc[i];
        }
      }
      union { u16 h[8]; f16x8 f; uint4 u; } av;
#pragma unroll
      for (int i = 0; i < 8; ++i) av.h[i] = __half_as_ushort(__float2half(v[i]));
      *(uint4*)(featC + (((size_t)(s * NKB + kb) * CHN + c) * 32 + q * 8)) = av.u;
      f16x8 bf = *(const f16x8*)(brow + ks * 32);
      acc = __builtin_amdgcn_mfma_f32_16x16x32_f16(av.f, bf, acc, 0, 0, 0);
    }
  } else {
    const u16* arow = featC + ((size_t)(s * NKB + kq * 12) * CHN + c) * 32 + q * 8;
#pragma unroll
    for (int ks = 0; ks < 12; ++ks) {
      f16x8 a = *(const f16x8*)(arow + (size_t)ks * (CHN * 32));
      f16x8 bf = *(const f16x8*)(brow + ks * 32);
      acc = __builtin_amdgcn_mfma_f32_16x16x32_f16(a, bf, acc, 0, 0, 0);
    }
  }
  if (kq) *(f32x4*)&kred[(((kq - 1) * 4 + tile) * 64 + lane) * 4] = acc;
  __syncthreads();

  // ---- phase 4: epilogue (kq==0 waves): w update, wg/wgf16 write, partials ----
  float num_part = 0.f, wsq_part = 0.f;
  if (kq == 0) {
#pragma unroll
    for (int kk = 0; kk < 3; ++kk)
      acc += *(const f32x4*)&kred[((kk * 4 + tile) * 64 + lane) * 4];
    int tap = m16;
    int ccb = c0 + tile * 16 + q * 4;  // base c of this lane's 4 rows
    union { u16 h[4]; uint2 v2; } pk;
#pragma unroll
    for (int r = 0; r < 4; ++r) {
      int cc = ccb + r;
      size_t widx = (size_t)s * 8192 + (size_t)cc * 16 + tap;
      float wold = wmaster[widx];
      float wnew = wold;
      if (t >= 1) {
        wnew = wold - step * alpha_p * wg[widx];
        wmaster[widx] = wnew;
      }
      float wgn = acc[r] + reg * wnew;
      wg[widx] = wgn;
      pk.h[r] = __half_as_ushort(__float2half(wgn));
      wsq_part += wnew * wnew;
      num_part += wgn * wgn;
    }
    *(uint2*)&wgf16[(size_t)s * 8192 + (size_t)tap * 512 + ccb] = pk.v2;
  }
  num_part = waveSum(num_part);
  wsq_part = waveSum(wsq_part);
  if (lane == 0) {
    nred[wave] = num_part;
    wred[wave] = wsq_part;
  }
  __syncthreads();
  if (tid == 0) {
    float nsum = 0.f, wsum = 0.f;
#pragma unroll
    for (int i = 0; i < 16; ++i) {
      nsum += nred[i];
      wsum += wred[i];
    }
    part[P_NUM + (size_t)(t * NS + s) * 8 + chunk] = nsum;
    if (t >= 1) part[P_WSQA + (size_t)((t - 1) * NS + s) * 8 + chunk] = wsum;
  }
}

// ---------------- k_den: per-s sum of sgraw4^2 (for k_final's alpha4) --------------
__global__ __launch_bounds__(1024) void k_den(const float* __restrict__ sga,
                                              const float* __restrict__ sgb,
                                              float* __restrict__ part) {
  __shared__ float dend[16];
  int s = blockIdx.x, tid = threadIdx.x;
  float dp = 0.f;
  for (int pl = tid; pl < 1587; pl += 1024) {
    int nn = (unsigned)pl / (unsigned)P2;
    int rem = pl - nn * P2;
    size_t gp = (size_t)(nn * NS + s) * P2 + rem;
    float g = sga[gp] + sgb[gp];
    dp += g * g;
  }
  dp = waveSum(dp);
  if ((tid & 63) == 0) dend[tid >> 6] = dp;
  __syncthreads();
  if (tid == 0) {
    float de = 0.f;
#pragma unroll
    for (int i = 0; i < 16; ++i) de += dend[i];
    part[P_DEN + s] = de * (1.0f / 3.0f);
  }
}

__device__ __forceinline__ float alphaFinal(const float* __restrict__ part, int s,
                                            float reg) {
  const float* np_ = part + P_NUM + (size_t)(4 * NS + s) * 8;
  float nu = 0.f;
#pragma unroll
  for (int i = 0; i < 8; ++i) nu += np_[i];
  float de = part[P_DEN + s];
  return nu / fmaxf(de + reg * nu, 1e-8f);
}

// ---------------- final: w5 update + final residual loss parts ----------------
__global__ void k_final(float* __restrict__ wmaster, const float* __restrict__ wg,
                        const float* __restrict__ scores4, const float* __restrict__ sga,
                        const float* __restrict__ sgb, const float* __restrict__ label,
                        float* __restrict__ part, const float* __restrict__ lsl,
                        const float* __restrict__ fr) {
  __shared__ float alpha_s[32];
  __shared__ float red4[4];
  int b = blockIdx.x, tid = threadIdx.x;
  float step = __expf(lsl[0]);
  float frv = fr[0];
  float reg = fmaxf(frv * frv, 1e-6f);
  if (tid < 32) alpha_s[tid] = alphaFinal(part, tid, reg);
  __syncthreads();
  if (b < 1024) {
    int idx = b * 256 + tid;  // 1024*256 == 262144 exactly
    int s = idx >> 13;        // uniform per block
    float w5 = wmaster[idx] - step * alpha_s[s] * wg[idx];
    wmaster[idx] = w5;
    float sq = waveSum(w5 * w5);
    if ((tid & 63) == 0) red4[tid >> 6] = sq;
    __syncthreads();
    if (tid == 0) part[P_WSQ5 + b] = red4[0] + red4[1] + red4[2] + red4[3];
  } else {
    int p = (b - 1024) * 256 + tid;
    float contrib = 0.f;
    if (p < NP) {
      int nsid = p / P2;
      int s = nsid & 31;  // nsid = n*NS + s
      float s5 = scores4[p] - step * alpha_s[s] * (sga[p] + sgb[p]);
      float d = s5 - label[p];
      contrib = d * d;
    }
    contrib = waveSum(contrib);
    if ((tid & 63) == 0) red4[tid >> 6] = contrib;
    __syncthreads();
    if (tid == 0)
      part[P_L5 + (b - 1024)] = (red4[0] + red4[1] + red4[2] + red4[3]) * (1.0f / 3.0f);
  }
}

// ---------------- losses: deterministic sums of all partials ----------------
__global__ void k_losses(float* __restrict__ out_losses, const float* __restrict__ part,
                         const float* __restrict__ fr) {
  __shared__ float red[8];
  int tid = threadIdx.x;  // 256
  float frv = fr[0];
  float reg = fmaxf(frv * frv, 1e-6f);
  float v5 = 0.f;
  for (int i = tid; i < 1024; i += 256) v5 += part[P_WSQ5 + i];
  v5 = waveSum(v5);
  if ((tid & 63) == 0) red[tid >> 6] = v5;
  __syncthreads();
  float wsq5 = red[0] + red[1] + red[2] + red[3];
  float l5 = 0.f;
  for (int i = tid; i < 199; i += 256) l5 += part[P_L5 + i];
  l5 = waveSum(l5);
  if ((tid & 63) == 0) red[4 + (tid >> 6)] = l5;
  __syncthreads();
  float loss5 = red[4] + red[5] + red[6] + red[7];
  if (tid < 5) {
    int t = tid;
    float ls = 0.f;
    for (int i = 0; i < 32; ++i) ls += part[P_LOSS + t * NS + i];
    float ws_ = 0.f;
    if (t == 0) {
      for (int i = 0; i < 32; ++i) ws_ += part[P_WSQ0 + i];
    } else {
      for (int i = 0; i < 256; ++i) ws_ += part[P_WSQA + (t - 1) * 256 + i];
    }
    out_losses[t] = (ls + reg * ws_) * (1.0f / 32.0f);
  }
  if (tid == 5) out_losses[5] = (loss5 + reg * wsq5) * (1.0f / 32.0f);
}

// ---------------- launch ----------------
extern "C" void kernel_launch(void* const* d_in, const int* in_sizes, int n_in,
                              void* d_out, int out_size, void* d_ws, size_t ws_size,
                              hipStream_t stream) {
  const float* w0 = (const float*)d_in[0];
  const float* feat = (const float*)d_in[1];
  const float* bb = (const float*)d_in[2];
  const float* lsl = (const float*)d_in[3];
  const float* fr = (const float*)d_in[4];
  float* out = (float*)d_out;
  char* ws = (char*)d_ws;
  u16* featT = (u16*)(ws + OFF_FEATT);
  float* label = (float*)(ws + OFF_LABEL);
  float* s0 = (float*)(ws + OFF_S0);
  float* s0b = (float*)(ws + OFF_S0B);
  float* s1 = (float*)(ws + OFF_S1);
  float* sga = (float*)(ws + OFF_SGRAW);
  float* sgb = (float*)(ws + OFF_SGB);
  float* wg = (float*)(ws + OFF_WG);
  u16* wgf16 = (u16*)(ws + OFF_WGF16);
  u16* w0f16 = (u16*)(ws + OFF_W0F16);
  float* part = (float*)(ws + OFF_PART);
  u16* featC = (u16*)(ws + OFF_FEATC);

  k_setup<<<1767, 256, 0, stream>>>(feat, w0, bb, featT, w0f16, out, label, part);
  // initial scores_0 partials = A * w0  (A half / B half)
  k_conv_fwd<<<192, 1024, 0, stream>>>(featT, w0f16, s0, s0b);
  // merged scores ping-pong: t=1 writes s1, t=2 writes s0 (s0a dead after t=1), ...
  for (int t = 0; t < 5; ++t) {
    const float* so = (t <= 1) ? s0 : ((t & 1) ? s0 : s1);  // t=2,4 read s1; t=3 reads s0
    float* sn = (t & 1) ? s1 : s0;                          // t=1->s1, t=2->s0, ...
    k_adjoint<<<256, 1024, 0, stream>>>(t, feat, featC, label, s0, s0b, so, sn, sga, sgb,
                                        wg, wgf16, out, part, lsl, fr);
    k_conv_fwd<<<192, 1024, 0, stream>>>(featT, wgf16, sga, sgb);
  }
  // merged scores_4 lives in s0 (t=4 wrote sn=s0); sgraw4 partials in sga/sgb
  k_den<<<32, 1024, 0, stream>>>(sga, sgb, part);
  k_final<<<1223, 256, 0, stream>>>(out, wg, s0, sga, sgb, label, part, lsl, fr);
  k_losses<<<1, 256, 0, stream>>>(out + WSZ, part, fr);
}

// Round 13
// 345.626 us; speedup vs baseline: 1.2593x; 1.0419x over previous
//
#include <hip/hip_runtime.h>
#include <hip/hip_fp16.h>

// ---------------- problem constants ----------------
#define NI 3
#define NS 32
#define CHN 512
#define OH 23
#define P2 529          // 23*23
#define NP 50784        // NI*NS*P2
#define UV 484          // 22*22
#define WSZ 262144      // NS*CHN*16
#define KTOT 1536       // 3n * 512 (uv padded 484->512)
#define NKB 48          // KTOT/32 k-blocks
#define RSP 1544        // Rs LDS pitch in halves (16B-aligned rows, bank-stagger)

typedef unsigned int uint32;
typedef unsigned short u16;
typedef _Float16 h2 __attribute__((ext_vector_type(2)));
typedef _Float16 f16x8 __attribute__((ext_vector_type(8)));
typedef float f32x4 __attribute__((ext_vector_type(4)));

// ---------------- workspace layout (bytes) ----------------
// featT layout: [snT(96)][cb4(4)][uv(484)][c(128)] f16, snT = s*3+n
// featC layout (k-blocked): [s(32)][kb(48)][c(512)][32] f16, k = kb*32+kk = n*512+uv
//   (uv 484..511 zero). Written by k_adjoint t=0 as a byproduct; read t>=1.
// sgp: [chunk(8)][n*NS+s][P2] f32 — per-chunk partial forward scores (A_chunk · wg_chunk)
#define OFF_FEATT 0UL           // 23,789,568 halves = 47,579,136 B
#define OFF_LABEL 47579136UL    // 50784 f32
#define OFF_S0    47782272UL    // 50784 f32 (scores partial A / merged ping)
#define OFF_S1    47985408UL    // 50784 f32 (merged pong)
#define OFF_WG    48391680UL    // 262144 f32
#define OFF_WGF16 49440256UL    // (unused)
#define OFF_W0F16 49964544UL    // 262144 f16, layout [s][tap][c]
#define OFF_PART  50488832UL    // partial-sum arrays (float), ~32 KB
#define OFF_FEATC 50521600UL    // 32*48*512*32 f16 = 50,331,648 B
#define OFF_S0B   100853248UL   // 50784 f32 (scores partial B)
#define OFF_SGP   101259520UL   // 8 x 50784 f32 = 1,625,088 B

// partial-array float indices — each slot written by exactly ONE block; NO atomics.
#define P_DEN   0       // [32] : per-s sum sgraw4^2 /3 (written by k_den)
#define P_NUM   4320    // [5][32][8]  : per-(t,s,chunk) sum wg^2 partials
#define P_LOSS  5600    // [5][32]     : per-(t,s) residual-loss partials
#define P_WSQ0  5760    // [32]        : sum w0^2 per s
#define P_WSQA  5792    // [4][32][8]  : sum w_t^2 partials, t=1..4
#define P_WSQ5  6816    // [1024]      : sum w5^2 per block
#define P_L5    7840    // [199]       : final loss per block

__device__ __forceinline__ float waveSum(float v) {
#pragma unroll
  for (int o = 32; o > 0; o >>= 1) v += __shfl_xor(v, o, 64);
  return v;
}

// ---------------- setup: feat->f16 transpose to featT, + w, label --------------------
__global__ __launch_bounds__(256) void k_setup(const float* __restrict__ feat,
                                               const float* __restrict__ w0,
                                               const float* __restrict__ bb,
                                               u16* __restrict__ featT,
                                               u16* __restrict__ w0f16,
                                               float* __restrict__ wmaster,
                                               float* __restrict__ label,
                                               float* __restrict__ part) {
  __shared__ uint32 lds32[64 * 121];  // [64 c][242 uv] f16 as u32 pairs, pitch 121
  __shared__ float sred[4];
  int b = blockIdx.x, tid = threadIdx.x;
  if (b < 1536) {
    int snT = b >> 4, r4 = b & 15;
    int cb = r4 >> 1, uvh = r4 & 1;  // 64-ch group, 242-uv half
    int s = snT / 3, n = snT % 3;
    const float* fsrc =
        feat + ((size_t)n * NS + s) * CHN * UV + (size_t)(cb * 64) * UV + uvh * 242;
#pragma unroll
    for (int it = 0; it < 31; ++it) {
      int idx = it * 256 + tid;
      if (idx < 7744) {
        int r = (unsigned)idx / 121u;
        int j = idx - r * 121;
        float2 v = *(const float2*)(fsrc + (size_t)r * UV + 2 * j);
        lds32[idx] = (uint32)__half_as_ushort(__float2half(v.x)) |
                     ((uint32)__half_as_ushort(__float2half(v.y)) << 16);
      }
    }
    __syncthreads();
    uint32* dstT = (uint32*)featT +
                   ((size_t)(snT * 4 + (cb >> 1)) * UV + uvh * 242) * 64 + (cb & 1) * 32;
#pragma unroll
    for (int it = 0; it < 16; ++it) {
      int o = it * 256 + tid;
      if (o < 3872) {
        int uv = o >> 4, kp = o & 15;
        int j = uv >> 1, sh = (uv & 1) * 16;
        uint32 a0 = lds32[(4 * kp + 0) * 121 + j];
        uint32 a1 = lds32[(4 * kp + 1) * 121 + j];
        uint32 a2 = lds32[(4 * kp + 2) * 121 + j];
        uint32 a3 = lds32[(4 * kp + 3) * 121 + j];
        uint2 val;
        val.x = ((a0 >> sh) & 0xffffu) | (((a1 >> sh) & 0xffffu) << 16);
        val.y = ((a2 >> sh) & 0xffffu) | (((a3 >> sh) & 0xffffu) << 16);
        *(uint2*)(dstT + (size_t)uv * 64 + 2 * kp) = val;
      }
    }
  } else if (b < 1568) {
    int s = b - 1536;
    for (int i = tid; i < 8192; i += 256) {
      int tap = i >> 9, c = i & 511;
      w0f16[(size_t)s * 8192 + i] =
          __half_as_ushort(__float2half(w0[(size_t)s * 8192 + c * 16 + tap]));
    }
    float sq = 0.f;
    for (int i = tid; i < 8192; i += 256) {
      float v = w0[(size_t)s * 8192 + i];
      wmaster[(size_t)s * 8192 + i] = v;
      sq += v * v;
    }
    sq = waveSum(sq);
    if ((tid & 63) == 0) sred[tid >> 6] = sq;
    __syncthreads();
    if (tid == 0) part[P_WSQ0 + s] = sred[0] + sred[1] + sred[2] + sred[3];
  } else {
    int p = (b - 1568) * 256 + tid;
    if (p < NP) {
      int nsid = p / P2, rem = p % P2;
      int i = rem / OH, j = rem % OH;
      const float* bp = bb + (size_t)nsid * 4;
      float cr = (bp[1] + 0.5f * bp[3]) * 0.0625f;
      float cc = (bp[0] + 0.5f * bp[2]) * 0.0625f;
      float dy = (float)i - cr, dx = (float)j - cc;
      label[p] = __expf(-0.5f * (dy * dy + dx * dx));
    }
  }
}

// ---------------- forward conv via MFMA, K(channel)-split (scores_0 only) -----------
// grid = 96 snT x 2 ch = 192 blocks x 1024 (16 waves; wave w owns M-tiles w, w+16).
__global__ __launch_bounds__(1024) void k_conv_fwd(const u16* __restrict__ featT,
                                                   const u16* __restrict__ wf16,
                                                   float* __restrict__ outA,
                                                   float* __restrict__ outB) {
  __shared__ uint32 w_lds[16 * 132];  // [tap][c-pair of this half], pitch 132
  __shared__ float G[496 * 17];       // [uv-row][tap], 31 tiles
  int tid = threadIdx.x;
  int bidx = blockIdx.x;
  int snT = bidx >> 1, ch = bidx & 1;
  int s = snT / 3, n = snT - s * 3;
  const uint32* wsrc = (const uint32*)(wf16 + (size_t)s * 8192) + ch * 128;
  for (int i = tid; i < 2048; i += 1024) {
    int tap = i >> 7, p = i & 127;
    w_lds[tap * 132 + p] = wsrc[(size_t)tap * 256 + p];
  }
  __syncthreads();
  int wave = tid >> 6, lane = tid & 63;
  int q = lane >> 4, m16 = lane & 15;
  int t0 = wave, t1 = wave + 16;
  bool has2 = (t1 < 31);
  f32x4 acc0 = {0.f, 0.f, 0.f, 0.f}, acc1 = {0.f, 0.f, 0.f, 0.f};
  size_t base = (size_t)snT * 4 * UV * 128;
  int r0i = t0 * 16 + m16;                 // <= 255
  int r1i = has2 ? t1 * 16 + m16 : 483;
  if (r1i > 483) r1i = 483;                // tile 30 pad rows: clamp (never gathered)
  size_t row0 = (size_t)r0i * 128;
  size_t row1 = (size_t)r1i * 128;
#pragma unroll
  for (int ks = 0; ks < 8; ++ks) {
    int cb = ch * 2 + (ks >> 2), cin = (ks & 3) * 32;
    size_t cbase = base + (size_t)cb * UV * 128 + cin + q * 8;
    f16x8 a0 = *(const f16x8*)(featT + cbase + row0);
    uint4 bw = *(const uint4*)&w_lds[m16 * 132 + ks * 16 + q * 4];
    f16x8 bf = __builtin_bit_cast(f16x8, bw);
    acc0 = __builtin_amdgcn_mfma_f32_16x16x32_f16(a0, bf, acc0, 0, 0, 0);
    if (has2) {
      f16x8 a1 = *(const f16x8*)(featT + cbase + row1);
      acc1 = __builtin_amdgcn_mfma_f32_16x16x32_f16(a1, bf, acc1, 0, 0, 0);
    }
  }
#pragma unroll
  for (int r = 0; r < 4; ++r) G[(t0 * 16 + q * 4 + r) * 17 + m16] = acc0[r];
  if (has2) {
#pragma unroll
    for (int r = 0; r < 4; ++r) G[(t1 * 16 + q * 4 + r) * 17 + m16] = acc1[r];
  }
  __syncthreads();
  if (tid < P2) {
    int y = tid / 23, x = tid - y * 23;
    float val = 0.f;
#pragma unroll
    for (int ky = 0; ky < 4; ++ky) {
      int u = y + ky - 2;
      if ((unsigned)u < 22u) {
#pragma unroll
        for (int kx = 0; kx < 4; ++kx) {
          int v = x + kx - 2;
          if ((unsigned)v < 22u) val += G[(u * 22 + v) * 17 + ky * 4 + kx];
        }
      }
    }
    float* dst = ch ? outB : outA;
    dst[(size_t)(n * NS + s) * P2 + tid] = val;
  }
}

// ---------------- adjoint + FUSED forward conv (phase 5) ----------------
// Per (s, chunk of 64 c): D[c,tap] = sum_k A[c,k] * Rs[tap,k], K=1536; then compute
// the chunk's partial of the NEXT forward scores sgp[chunk] = gather(A_chunk · wg_chunk).
// sgraw(t) = sum_{chunk} sgp[chunk], summed in fixed order by consumers.
// grid = 32 s * 8 chunks = 256 blocks x 1024 (16 waves: tile=wave&3, kq=wave>>2).
__global__ __launch_bounds__(1024) void k_adjoint(
    int t, const float* __restrict__ feat, const u16* __restrict__ featT,
    u16* __restrict__ featC, const float* __restrict__ label,
    const float* __restrict__ s0a, const float* __restrict__ s0b,
    const float* __restrict__ scores_old, float* __restrict__ scores_new,
    float* __restrict__ sgp, float* __restrict__ wg, float* __restrict__ wmaster,
    float* __restrict__ part, const float* __restrict__ lsl,
    const float* __restrict__ fr) {
  __shared__ float r_lds[3 * P2];              // rm = sw^2 * resid, [n][y*23+x]
  __shared__ float g_lds[1587];                // merged sgraw cache (phase0 -> phase1)
  __shared__ __align__(16) union ShPool {
    u16 rs[16 * RSP];                          // phases 2-3: Rs [tap][k]
    float G[496 * 17];                         // phase 5: partial G [uv-row][tap]
  } shp;
  __shared__ __align__(16) float kred[3 * 4 * 64 * 4];
  __shared__ __align__(8) u16 wgB[16 * 72];    // [tap][c_local], pitch 72 (stagger)
  __shared__ float lred[16], nred[16], wred[16], dend[16];
  int tid = threadIdx.x;
  int s = blockIdx.x >> 3, chunk = blockIdx.x & 7;
  int c0 = chunk * 64;
  float step = __expf(lsl[0]);
  float frv = fr[0];
  float reg = fmaxf(frv * frv, 1e-6f);

  // ---- phase 0: alpha_{t-1} from P_NUM + block-local sum of (sum_ch sgp)^2 ----
  float alpha_p = 0.f;
  if (t >= 1) {
    const float* np_ = part + P_NUM + (size_t)((t - 1) * NS + s) * 8;
    float nu = 0.f;
#pragma unroll
    for (int i = 0; i < 8; ++i) nu += np_[i];
    float dp = 0.f;
    for (int pl = tid; pl < 1587; pl += 1024) {
      int nn = (unsigned)pl / (unsigned)P2;
      int rem = pl - nn * P2;
      size_t gp = (size_t)(nn * NS + s) * P2 + rem;
      float g = 0.f;
#pragma unroll
      for (int ch = 0; ch < 8; ++ch) g += sgp[(size_t)ch * NP + gp];
      g_lds[pl] = g;
      dp += g * g;
    }
    dp = waveSum(dp);
    if ((tid & 63) == 0) dend[tid >> 6] = dp;
    __syncthreads();
    float de = 0.f;
#pragma unroll
    for (int i = 0; i < 16; ++i) de += dend[i];
    alpha_p = nu / fmaxf(de * (1.0f / 3.0f) + reg * nu, 1e-8f);
  }

  // ---- phase 1: residuals (+ scores recurrence, loss on chunk 0) ----
  float lsum = 0.f;
  for (int pl = tid; pl < 1587; pl += 1024) {
    int nn = (unsigned)pl / (unsigned)P2;
    int rem = pl - nn * P2;
    size_t gp = (size_t)(nn * NS + s) * P2 + rem;
    float S = (t <= 1) ? (s0a[gp] + s0b[gp]) : scores_old[gp];
    if (t >= 1) S -= step * alpha_p * g_lds[pl];
    float d = S - label[gp];
    r_lds[nn * P2 + rem] = d * (1.0f / 3.0f);
    if (chunk == 0) {
      if (t >= 1) scores_new[gp] = S;
      lsum += d * d;
    }
  }
  lsum = waveSum(lsum);
  if ((tid & 63) == 0) lred[tid >> 6] = lsum;
  __syncthreads();
  if (chunk == 0 && tid == 0) {
    float L = 0.f;
#pragma unroll
    for (int i = 0; i < 16; ++i) L += lred[i];
    part[P_LOSS + t * NS + s] = L * (1.0f / 3.0f);
  }

  // ---- phase 2: build Rs [tap][k] f16 in LDS ----
  for (int idx = tid; idx < 16 * RSP; idx += 1024) {
    int tap = (unsigned)idx / (unsigned)RSP;
    int k = idx - tap * RSP;
    float val = 0.f;
    if (k < KTOT) {
      int n = k >> 9, uv = k & 511;
      if (uv < UV) {
        int u = (unsigned)uv / 22u;
        int v = uv - u * 22;
        int ky = tap >> 2, kx = tap & 3;
        int y = u + 2 - ky, x = v + 2 - kx;
        if ((unsigned)y < 23u && (unsigned)x < 23u) val = r_lds[n * P2 + y * OH + x];
      }
    }
    shp.rs[idx] = __half_as_ushort(__float2half(val));
  }
  __syncthreads();

  // ---- phase 3: MFMA GEMM, 4 M-tiles x 4 K-quarters (12 K-steps each) ----
  int wave = tid >> 6, lane = tid & 63;
  int q = lane >> 4, m16 = lane & 15;
  int tile = wave & 3, kq = wave >> 2;
  int c = c0 + tile * 16 + m16;
  const u16* brow = shp.rs + m16 * RSP + kq * 384 + q * 8;
  f32x4 acc = {0.f, 0.f, 0.f, 0.f};
  if (t == 0) {
#pragma unroll
    for (int ks = 0; ks < 12; ++ks) {
      int kb = kq * 12 + ks;
      int k0 = kb * 32 + q * 8;
      int nn = k0 >> 9, uv0 = k0 & 511;
      float v[8];
#pragma unroll
      for (int i = 0; i < 8; ++i) v[i] = 0.f;
      if (uv0 < UV) {
        const float* fsrc = feat + ((size_t)(nn * NS + s) * CHN + c) * UV + uv0;
        if (uv0 + 8 <= UV) {
          float4 p0 = *(const float4*)fsrc;
          float4 p1 = *(const float4*)(fsrc + 4);
          v[0] = p0.x; v[1] = p0.y; v[2] = p0.z; v[3] = p0.w;
          v[4] = p1.x; v[5] = p1.y; v[6] = p1.z; v[7] = p1.w;
        } else {  // uv0 == 480: 4 valid
#pragma unroll
          for (int i = 0; i < 4; ++i) v[i] = fsrc[i];
        }
      }
      union { u16 h[8]; f16x8 f; uint4 u; } av;
#pragma unroll
      for (int i = 0; i < 8; ++i) av.h[i] = __half_as_ushort(__float2half(v[i]));
      *(uint4*)(featC + (((size_t)(s * NKB + kb) * CHN + c) * 32 + q * 8)) = av.u;
      f16x8 bf = *(const f16x8*)(brow + ks * 32);
      acc = __builtin_amdgcn_mfma_f32_16x16x32_f16(av.f, bf, acc, 0, 0, 0);
    }
  } else {
    const u16* arow = featC + ((size_t)(s * NKB + kq * 12) * CHN + c) * 32 + q * 8;
#pragma unroll
    for (int ks = 0; ks < 12; ++ks) {
      f16x8 a = *(const f16x8*)(arow + (size_t)ks * (CHN * 32));
      f16x8 bf = *(const f16x8*)(brow + ks * 32);
      acc = __builtin_amdgcn_mfma_f32_16x16x32_f16(a, bf, acc, 0, 0, 0);
    }
  }
  if (kq) *(f32x4*)&kred[(((kq - 1) * 4 + tile) * 64 + lane) * 4] = acc;
  __syncthreads();

  // ---- phase 4: epilogue (kq==0 waves): w update, wg write, wgB LDS, partials ----
  float num_part = 0.f, wsq_part = 0.f;
  if (kq == 0) {
#pragma unroll
    for (int kk = 0; kk < 3; ++kk)
      acc += *(const f32x4*)&kred[((kk * 4 + tile) * 64 + lane) * 4];
    int tap = m16;
    int ccb = c0 + tile * 16 + q * 4;  // base c of this lane's 4 rows
    union { u16 h[4]; uint2 v2; } pk;
#pragma unroll
    for (int r = 0; r < 4; ++r) {
      int cc = ccb + r;
      size_t widx = (size_t)s * 8192 + (size_t)cc * 16 + tap;
      float wold = wmaster[widx];
      float wnew = wold;
      if (t >= 1) {
        wnew = wold - step * alpha_p * wg[widx];
        wmaster[widx] = wnew;
      }
      float wgn = acc[r] + reg * wnew;
      wg[widx] = wgn;
      pk.h[r] = __half_as_ushort(__float2half(wgn));
      wsq_part += wnew * wnew;
      num_part += wgn * wgn;
    }
    *(uint2*)&wgB[m16 * 72 + tile * 16 + q * 4] = pk.v2;
  }
  num_part = waveSum(num_part);
  wsq_part = waveSum(wsq_part);
  if (lane == 0) {
    nred[wave] = num_part;
    wred[wave] = wsq_part;
  }
  __syncthreads();
  if (tid == 0) {
    float nsum = 0.f, wsum = 0.f;
#pragma unroll
    for (int i = 0; i < 16; ++i) {
      nsum += nred[i];
      wsum += wred[i];
    }
    part[P_NUM + (size_t)(t * NS + s) * 8 + chunk] = nsum;
    if (t >= 1) part[P_WSQA + (size_t)((t - 1) * NS + s) * 8 + chunk] = wsum;
  }
  __syncthreads();  // wgB visible to all; rs reads done -> G may overwrite

  // ---- phase 5: fused forward — partial scores for THIS chunk (A_chunk · wg_chunk) --
  f16x8 bf0 = *(const f16x8*)&wgB[m16 * 72 + q * 8];
  f16x8 bf1 = *(const f16x8*)&wgB[m16 * 72 + 32 + q * 8];
  int cbb = chunk >> 1;
  int chalf = (chunk & 1) * 64;
  for (int n = 0; n < 3; ++n) {
    int snT = s * 3 + n;
    const u16* ab = featT + (size_t)(snT * 4 + cbb) * UV * 128 + chalf + q * 8;
    {
      int r0 = wave * 16 + m16;  // <= 255
      const u16* ap = ab + (size_t)r0 * 128;
      f32x4 a0 = {0.f, 0.f, 0.f, 0.f};
      a0 = __builtin_amdgcn_mfma_f32_16x16x32_f16(*(const f16x8*)ap, bf0, a0, 0, 0, 0);
      a0 = __builtin_amdgcn_mfma_f32_16x16x32_f16(*(const f16x8*)(ap + 32), bf1, a0, 0,
                                                  0, 0);
#pragma unroll
      for (int r = 0; r < 4; ++r) shp.G[(wave * 16 + q * 4 + r) * 17 + m16] = a0[r];
      if (wave < 15) {
        int r1 = (wave + 16) * 16 + m16;
        if (r1 > 483) r1 = 483;  // tile 30 pad rows: clamp (never gathered)
        const u16* ap1 = ab + (size_t)r1 * 128;
        f32x4 a1 = {0.f, 0.f, 0.f, 0.f};
        a1 = __builtin_amdgcn_mfma_f32_16x16x32_f16(*(const f16x8*)ap1, bf0, a1, 0, 0, 0);
        a1 = __builtin_amdgcn_mfma_f32_16x16x32_f16(*(const f16x8*)(ap1 + 32), bf1, a1,
                                                    0, 0, 0);
#pragma unroll
        for (int r = 0; r < 4; ++r)
          shp.G[((wave + 16) * 16 + q * 4 + r) * 17 + m16] = a1[r];
      }
    }
    __syncthreads();
    if (tid < P2) {
      int y = tid / 23, x = tid - y * 23;
      float val = 0.f;
#pragma unroll
      for (int ky = 0; ky < 4; ++ky) {
        int u = y + ky - 2;
        if ((unsigned)u < 22u) {
#pragma unroll
          for (int kx = 0; kx < 4; ++kx) {
            int v = x + kx - 2;
            if ((unsigned)v < 22u) val += shp.G[(u * 22 + v) * 17 + ky * 4 + kx];
          }
        }
      }
      sgp[(size_t)chunk * NP + (size_t)(n * NS + s) * P2 + tid] = val;
    }
    __syncthreads();
  }
}

// ---------------- k_den: per-s sum of sgraw4^2 (for k_final's alpha4) --------------
__global__ __launch_bounds__(1024) void k_den(const float* __restrict__ sgp,
                                              float* __restrict__ part) {
  __shared__ float dend[16];
  int s = blockIdx.x, tid = threadIdx.x;
  float dp = 0.f;
  for (int pl = tid; pl < 1587; pl += 1024) {
    int nn = (unsigned)pl / (unsigned)P2;
    int rem = pl - nn * P2;
    size_t gp = (size_t)(nn * NS + s) * P2 + rem;
    float g = 0.f;
#pragma unroll
    for (int ch = 0; ch < 8; ++ch) g += sgp[(size_t)ch * NP + gp];
    dp += g * g;
  }
  dp = waveSum(dp);
  if ((tid & 63) == 0) dend[tid >> 6] = dp;
  __syncthreads();
  if (tid == 0) {
    float de = 0.f;
#pragma unroll
    for (int i = 0; i < 16; ++i) de += dend[i];
    part[P_DEN + s] = de * (1.0f / 3.0f);
  }
}

__device__ __forceinline__ float alphaFinal(const float* __restrict__ part, int s,
                                            float reg) {
  const float* np_ = part + P_NUM + (size_t)(4 * NS + s) * 8;
  float nu = 0.f;
#pragma unroll
  for (int i = 0; i < 8; ++i) nu += np_[i];
  float de = part[P_DEN + s];
  return nu / fmaxf(de + reg * nu, 1e-8f);
}

// ---------------- final: w5 update + final residual loss parts ----------------
__global__ void k_final(float* __restrict__ wmaster, const float* __restrict__ wg,
                        const float* __restrict__ scores4, const float* __restrict__ sgp,
                        const float* __restrict__ label, float* __restrict__ part,
                        const float* __restrict__ lsl, const float* __restrict__ fr) {
  __shared__ float alpha_s[32];
  __shared__ float red4[4];
  int b = blockIdx.x, tid = threadIdx.x;
  float step = __expf(lsl[0]);
  float frv = fr[0];
  float reg = fmaxf(frv * frv, 1e-6f);
  if (tid < 32) alpha_s[tid] = alphaFinal(part, tid, reg);
  __syncthreads();
  if (b < 1024) {
    int idx = b * 256 + tid;  // 1024*256 == 262144 exactly
    int s = idx >> 13;        // uniform per block
    float w5 = wmaster[idx] - step * alpha_s[s] * wg[idx];
    wmaster[idx] = w5;
    float sq = waveSum(w5 * w5);
    if ((tid & 63) == 0) red4[tid >> 6] = sq;
    __syncthreads();
    if (tid == 0) part[P_WSQ5 + b] = red4[0] + red4[1] + red4[2] + red4[3];
  } else {
    int p = (b - 1024) * 256 + tid;
    float contrib = 0.f;
    if (p < NP) {
      int nsid = p / P2;
      int s = nsid & 31;  // nsid = n*NS + s
      float g = 0.f;
#pragma unroll
      for (int ch = 0; ch < 8; ++ch) g += sgp[(size_t)ch * NP + p];
      float s5 = scores4[p] - step * alpha_s[s] * g;
      float d = s5 - label[p];
      contrib = d * d;
    }
    contrib = waveSum(contrib);
    if ((tid & 63) == 0) red4[tid >> 6] = contrib;
    __syncthreads();
    if (tid == 0)
      part[P_L5 + (b - 1024)] = (red4[0] + red4[1] + red4[2] + red4[3]) * (1.0f / 3.0f);
  }
}

// ---------------- losses: deterministic sums of all partials ----------------
__global__ void k_losses(float* __restrict__ out_losses, const float* __restrict__ part,
                         const float* __restrict__ fr) {
  __shared__ float red[8];
  int tid = threadIdx.x;  // 256
  float frv = fr[0];
  float reg = fmaxf(frv * frv, 1e-6f);
  float v5 = 0.f;
  for (int i = tid; i < 1024; i += 256) v5 += part[P_WSQ5 + i];
  v5 = waveSum(v5);
  if ((tid & 63) == 0) red[tid >> 6] = v5;
  __syncthreads();
  float wsq5 = red[0] + red[1] + red[2] + red[3];
  float l5 = 0.f;
  for (int i = tid; i < 199; i += 256) l5 += part[P_L5 + i];
  l5 = waveSum(l5);
  if ((tid & 63) == 0) red[4 + (tid >> 6)] = l5;
  __syncthreads();
  float loss5 = red[4] + red[5] + red[6] + red[7];
  if (tid < 5) {
    int t = tid;
    float ls = 0.f;
    for (int i = 0; i < 32; ++i) ls += part[P_LOSS + t * NS + i];
    float ws_ = 0.f;
    if (t == 0) {
      for (int i = 0; i < 32; ++i) ws_ += part[P_WSQ0 + i];
    } else {
      for (int i = 0; i < 256; ++i) ws_ += part[P_WSQA + (t - 1) * 256 + i];
    }
    out_losses[t] = (ls + reg * ws_) * (1.0f / 32.0f);
  }
  if (tid == 5) out_losses[5] = (loss5 + reg * wsq5) * (1.0f / 32.0f);
}

// ---------------- launch ----------------
extern "C" void kernel_launch(void* const* d_in, const int* in_sizes, int n_in,
                              void* d_out, int out_size, void* d_ws, size_t ws_size,
                              hipStream_t stream) {
  const float* w0 = (const float*)d_in[0];
  const float* feat = (const float*)d_in[1];
  const float* bb = (const float*)d_in[2];
  const float* lsl = (const float*)d_in[3];
  const float* fr = (const float*)d_in[4];
  float* out = (float*)d_out;
  char* ws = (char*)d_ws;
  u16* featT = (u16*)(ws + OFF_FEATT);
  float* label = (float*)(ws + OFF_LABEL);
  float* s0 = (float*)(ws + OFF_S0);
  float* s0b = (float*)(ws + OFF_S0B);
  float* s1 = (float*)(ws + OFF_S1);
  float* sgp = (float*)(ws + OFF_SGP);
  float* wg = (float*)(ws + OFF_WG);
  u16* w0f16 = (u16*)(ws + OFF_W0F16);
  float* part = (float*)(ws + OFF_PART);
  u16* featC = (u16*)(ws + OFF_FEATC);

  k_setup<<<1767, 256, 0, stream>>>(feat, w0, bb, featT, w0f16, out, label, part);
  // initial scores_0 partials = A * w0  (A half / B half)
  k_conv_fwd<<<192, 1024, 0, stream>>>(featT, w0f16, s0, s0b);
  // adjoint(t) also produces sgp = per-chunk partials of A·wg_t (fused forward)
  for (int t = 0; t < 5; ++t) {
    const float* so = (t <= 1) ? s0 : ((t & 1) ? s0 : s1);  // t=2,4 read s1; t=3 reads s0
    float* sn = (t & 1) ? s1 : s0;                          // t=1->s1, t=2->s0, ...
    k_adjoint<<<256, 1024, 0, stream>>>(t, feat, featT, featC, label, s0, s0b, so, sn,
                                        sgp, wg, out, part, lsl, fr);
  }
  // merged scores_4 lives in s0 (t=4 wrote sn=s0); sgraw4 partials in sgp
  k_den<<<32, 1024, 0, stream>>>(sgp, part);
  k_final<<<1223, 256, 0, stream>>>(out, wg, s0, sgp, label, part, lsl, fr);
  k_losses<<<1, 256, 0, stream>>>(out + WSZ, part, fr);
}

// Round 14
// 337.286 us; speedup vs baseline: 1.2904x; 1.0247x over previous
//
#include <hip/hip_runtime.h>
#include <hip/hip_fp16.h>

// ---------------- problem constants ----------------
#define NI 3
#define NS 32
#define CHN 512
#define OH 23
#define P2 529          // 23*23
#define NP 50784        // NI*NS*P2
#define UV 484          // 22*22
#define WSZ 262144      // NS*CHN*16
#define KTOT 1536       // 3n * 512 (uv padded 484->512)
#define NKB 48          // KTOT/32 k-blocks
#define RSP 1544        // Rs LDS pitch in halves (16B-aligned rows, bank-stagger)

typedef unsigned int uint32;
typedef unsigned short u16;
typedef _Float16 h2 __attribute__((ext_vector_type(2)));
typedef _Float16 f16x8 __attribute__((ext_vector_type(8)));
typedef float f32x4 __attribute__((ext_vector_type(4)));

// ---------------- workspace layout (bytes) ----------------
// featT layout: [snT(96)][cb4(4)][uv(484)][c(128)] f16, snT = s*3+n
// featC layout (k-blocked): [s(32)][kb(48)][c(512)][32] f16, k = kb*32+kk = n*512+uv
//   (uv 484..511 zero). Written by k_adjoint t=0 as a byproduct; read t>=1.
// sgp: [chunk(8)][n*NS+s][P2] f32 — per-chunk partial forward scores (A_chunk · wg_chunk)
#define OFF_FEATT 0UL           // 23,789,568 halves = 47,579,136 B
#define OFF_LABEL 47579136UL    // 50784 f32
#define OFF_S0    47782272UL    // 50784 f32 (scores partial A / merged ping)
#define OFF_S1    47985408UL    // 50784 f32 (merged pong)
#define OFF_WG    48391680UL    // 262144 f32
#define OFF_W0F16 49964544UL    // 262144 f16, layout [s][tap][c]
#define OFF_PART  50488832UL    // partial-sum arrays (float), ~32 KB
#define OFF_FEATC 50521600UL    // 32*48*512*32 f16 = 50,331,648 B
#define OFF_S0B   100853248UL   // 50784 f32 (scores partial B)
#define OFF_SGP   101259520UL   // 8 x 50784 f32 = 1,625,088 B

// partial-array float indices — each slot written by exactly ONE block; NO atomics.
#define P_DEN   0       // [32] : per-s sum sgraw4^2 /3 (written by k_den)
#define P_NUM   4320    // [5][32][8]  : per-(t,s,chunk) sum wg^2 partials
#define P_LOSS  5600    // [5][32]     : per-(t,s) residual-loss partials
#define P_WSQ0  5760    // [32]        : sum w0^2 per s
#define P_WSQA  5792    // [4][32][8]  : sum w_t^2 partials, t=1..4
#define P_WSQ5  6816    // [1024]      : sum w5^2 per block
#define P_L5    7840    // [199]       : final loss per block

__device__ __forceinline__ float waveSum(float v) {
#pragma unroll
  for (int o = 32; o > 0; o >>= 1) v += __shfl_xor(v, o, 64);
  return v;
}

// ---------------- setup: feat->f16 transpose to featT, + w, label --------------------
// transpose tile = (snT, cb of 64 ch, uvh of 242 uv): LDS [64 c][121 u32-pairs] = 31 KB
// 512 threads/block (8 waves): 4 blocks/CU x 8 = 32 waves/CU — full occupancy to hide
// the latency-bound f32 read stream (R12 PMC: 28% occupancy at 256 thr was the limiter).
// grid = 1536 (tiles) + 32 (w) + 100 (label) = 1668 blocks x 512
__global__ __launch_bounds__(512) void k_setup(const float* __restrict__ feat,
                                               const float* __restrict__ w0,
                                               const float* __restrict__ bb,
                                               u16* __restrict__ featT,
                                               u16* __restrict__ w0f16,
                                               float* __restrict__ wmaster,
                                               float* __restrict__ label,
                                               float* __restrict__ part) {
  __shared__ uint32 lds32[64 * 121];  // [64 c][242 uv] f16 as u32 pairs, pitch 121
  __shared__ float sred[8];
  int b = blockIdx.x, tid = threadIdx.x;
  if (b < 1536) {
    int snT = b >> 4, r4 = b & 15;
    int cb = r4 >> 1, uvh = r4 & 1;  // 64-ch group, 242-uv half
    int s = snT / 3, n = snT % 3;
    const float* fsrc =
        feat + ((size_t)n * NS + s) * CHN * UV + (size_t)(cb * 64) * UV + uvh * 242;
#pragma unroll
    for (int it = 0; it < 16; ++it) {
      int idx = it * 512 + tid;
      if (idx < 7744) {
        int r = (unsigned)idx / 121u;
        int j = idx - r * 121;
        float2 v = *(const float2*)(fsrc + (size_t)r * UV + 2 * j);
        lds32[idx] = (uint32)__half_as_ushort(__float2half(v.x)) |
                     ((uint32)__half_as_ushort(__float2half(v.y)) << 16);
      }
    }
    __syncthreads();
    uint32* dstT = (uint32*)featT +
                   ((size_t)(snT * 4 + (cb >> 1)) * UV + uvh * 242) * 64 + (cb & 1) * 32;
#pragma unroll
    for (int it = 0; it < 8; ++it) {
      int o = it * 512 + tid;
      if (o < 3872) {
        int uv = o >> 4, kp = o & 15;
        int j = uv >> 1, sh = (uv & 1) * 16;
        uint32 a0 = lds32[(4 * kp + 0) * 121 + j];
        uint32 a1 = lds32[(4 * kp + 1) * 121 + j];
        uint32 a2 = lds32[(4 * kp + 2) * 121 + j];
        uint32 a3 = lds32[(4 * kp + 3) * 121 + j];
        uint2 val;
        val.x = ((a0 >> sh) & 0xffffu) | (((a1 >> sh) & 0xffffu) << 16);
        val.y = ((a2 >> sh) & 0xffffu) | (((a3 >> sh) & 0xffffu) << 16);
        *(uint2*)(dstT + (size_t)uv * 64 + 2 * kp) = val;
      }
    }
  } else if (b < 1568) {
    int s = b - 1536;
    for (int i = tid; i < 8192; i += 512) {
      int tap = i >> 9, c = i & 511;
      w0f16[(size_t)s * 8192 + i] =
          __half_as_ushort(__float2half(w0[(size_t)s * 8192 + c * 16 + tap]));
    }
    float sq = 0.f;
    for (int i = tid; i < 8192; i += 512) {
      float v = w0[(size_t)s * 8192 + i];
      wmaster[(size_t)s * 8192 + i] = v;
      sq += v * v;
    }
    sq = waveSum(sq);
    if ((tid & 63) == 0) sred[tid >> 6] = sq;
    __syncthreads();
    if (tid == 0) {
      float t_ = 0.f;
#pragma unroll
      for (int i = 0; i < 8; ++i) t_ += sred[i];
      part[P_WSQ0 + s] = t_;
    }
  } else {
    int p = (b - 1568) * 512 + tid;
    if (p < NP) {
      int nsid = p / P2, rem = p % P2;
      int i = rem / OH, j = rem % OH;
      const float* bp = bb + (size_t)nsid * 4;
      float cr = (bp[1] + 0.5f * bp[3]) * 0.0625f;
      float cc = (bp[0] + 0.5f * bp[2]) * 0.0625f;
      float dy = (float)i - cr, dx = (float)j - cc;
      label[p] = __expf(-0.5f * (dy * dy + dx * dx));
    }
  }
}

// ---------------- forward conv via MFMA, K(channel)-split (scores_0 only) -----------
// grid = 96 snT x 2 ch = 192 blocks x 1024 (16 waves; wave w owns M-tiles w, w+16).
__global__ __launch_bounds__(1024) void k_conv_fwd(const u16* __restrict__ featT,
                                                   const u16* __restrict__ wf16,
                                                   float* __restrict__ outA,
                                                   float* __restrict__ outB) {
  __shared__ uint32 w_lds[16 * 132];  // [tap][c-pair of this half], pitch 132
  __shared__ float G[496 * 17];       // [uv-row][tap], 31 tiles
  int tid = threadIdx.x;
  int bidx = blockIdx.x;
  int snT = bidx >> 1, ch = bidx & 1;
  int s = snT / 3, n = snT - s * 3;
  const uint32* wsrc = (const uint32*)(wf16 + (size_t)s * 8192) + ch * 128;
  for (int i = tid; i < 2048; i += 1024) {
    int tap = i >> 7, p = i & 127;
    w_lds[tap * 132 + p] = wsrc[(size_t)tap * 256 + p];
  }
  __syncthreads();
  int wave = tid >> 6, lane = tid & 63;
  int q = lane >> 4, m16 = lane & 15;
  int t0 = wave, t1 = wave + 16;
  bool has2 = (t1 < 31);
  f32x4 acc0 = {0.f, 0.f, 0.f, 0.f}, acc1 = {0.f, 0.f, 0.f, 0.f};
  size_t base = (size_t)snT * 4 * UV * 128;
  int r0i = t0 * 16 + m16;                 // <= 255
  int r1i = has2 ? t1 * 16 + m16 : 483;
  if (r1i > 483) r1i = 483;                // tile 30 pad rows: clamp (never gathered)
  size_t row0 = (size_t)r0i * 128;
  size_t row1 = (size_t)r1i * 128;
#pragma unroll
  for (int ks = 0; ks < 8; ++ks) {
    int cb = ch * 2 + (ks >> 2), cin = (ks & 3) * 32;
    size_t cbase = base + (size_t)cb * UV * 128 + cin + q * 8;
    f16x8 a0 = *(const f16x8*)(featT + cbase + row0);
    uint4 bw = *(const uint4*)&w_lds[m16 * 132 + ks * 16 + q * 4];
    f16x8 bf = __builtin_bit_cast(f16x8, bw);
    acc0 = __builtin_amdgcn_mfma_f32_16x16x32_f16(a0, bf, acc0, 0, 0, 0);
    if (has2) {
      f16x8 a1 = *(const f16x8*)(featT + cbase + row1);
      acc1 = __builtin_amdgcn_mfma_f32_16x16x32_f16(a1, bf, acc1, 0, 0, 0);
    }
  }
#pragma unroll
  for (int r = 0; r < 4; ++r) G[(t0 * 16 + q * 4 + r) * 17 + m16] = acc0[r];
  if (has2) {
#pragma unroll
    for (int r = 0; r < 4; ++r) G[(t1 * 16 + q * 4 + r) * 17 + m16] = acc1[r];
  }
  __syncthreads();
  if (tid < P2) {
    int y = tid / 23, x = tid - y * 23;
    float val = 0.f;
#pragma unroll
    for (int ky = 0; ky < 4; ++ky) {
      int u = y + ky - 2;
      if ((unsigned)u < 22u) {
#pragma unroll
        for (int kx = 0; kx < 4; ++kx) {
          int v = x + kx - 2;
          if ((unsigned)v < 22u) val += G[(u * 22 + v) * 17 + ky * 4 + kx];
        }
      }
    }
    float* dst = ch ? outB : outA;
    dst[(size_t)(n * NS + s) * P2 + tid] = val;
  }
}

// ---------------- adjoint + FUSED forward conv (phase 5) ----------------
// Per (s, chunk of 64 c): D[c,tap] = sum_k A[c,k] * Rs[tap,k], K=1536; then compute
// the chunk's partial of the NEXT forward scores sgp[chunk] = gather(A_chunk · wg_chunk).
// sgraw(t) = sum_{chunk} sgp[chunk], summed in fixed order by consumers.
// grid = 32 s * 8 chunks = 256 blocks x 1024 (16 waves: tile=wave&3, kq=wave>>2).
__global__ __launch_bounds__(1024) void k_adjoint(
    int t, const float* __restrict__ feat, const u16* __restrict__ featT,
    u16* __restrict__ featC, const float* __restrict__ label,
    const float* __restrict__ s0a, const float* __restrict__ s0b,
    const float* __restrict__ scores_old, float* __restrict__ scores_new,
    float* __restrict__ sgp, float* __restrict__ wg, float* __restrict__ wmaster,
    float* __restrict__ part, const float* __restrict__ lsl,
    const float* __restrict__ fr) {
  __shared__ float r_lds[3 * P2];              // rm = sw^2 * resid, [n][y*23+x]
  __shared__ float g_lds[1587];                // merged sgraw cache (phase0 -> phase1)
  __shared__ __align__(16) union ShPool {
    u16 rs[16 * RSP];                          // phases 2-3: Rs [tap][k]
    float G[496 * 17];                         // phase 5: partial G [uv-row][tap]
  } shp;
  __shared__ __align__(16) float kred[3 * 4 * 64 * 4];
  __shared__ __align__(8) u16 wgB[16 * 72];    // [tap][c_local], pitch 72 (stagger)
  __shared__ float lred[16], nred[16], wred[16], dend[16];
  int tid = threadIdx.x;
  int s = blockIdx.x >> 3, chunk = blockIdx.x & 7;
  int c0 = chunk * 64;
  float step = __expf(lsl[0]);
  float frv = fr[0];
  float reg = fmaxf(frv * frv, 1e-6f);

  // ---- phase 0: alpha_{t-1} from P_NUM + block-local sum of (sum_ch sgp)^2 ----
  float alpha_p = 0.f;
  if (t >= 1) {
    const float* np_ = part + P_NUM + (size_t)((t - 1) * NS + s) * 8;
    float nu = 0.f;
#pragma unroll
    for (int i = 0; i < 8; ++i) nu += np_[i];
    float dp = 0.f;
    for (int pl = tid; pl < 1587; pl += 1024) {
      int nn = (unsigned)pl / (unsigned)P2;
      int rem = pl - nn * P2;
      size_t gp = (size_t)(nn * NS + s) * P2 + rem;
      float g = 0.f;
#pragma unroll
      for (int ch = 0; ch < 8; ++ch) g += sgp[(size_t)ch * NP + gp];
      g_lds[pl] = g;
      dp += g * g;
    }
    dp = waveSum(dp);
    if ((tid & 63) == 0) dend[tid >> 6] = dp;
    __syncthreads();
    float de = 0.f;
#pragma unroll
    for (int i = 0; i < 16; ++i) de += dend[i];
    alpha_p = nu / fmaxf(de * (1.0f / 3.0f) + reg * nu, 1e-8f);
  }

  // ---- phase 1: residuals (+ scores recurrence, loss on chunk 0) ----
  float lsum = 0.f;
  for (int pl = tid; pl < 1587; pl += 1024) {
    int nn = (unsigned)pl / (unsigned)P2;
    int rem = pl - nn * P2;
    size_t gp = (size_t)(nn * NS + s) * P2 + rem;
    float S = (t <= 1) ? (s0a[gp] + s0b[gp]) : scores_old[gp];
    if (t >= 1) S -= step * alpha_p * g_lds[pl];
    float d = S - label[gp];
    r_lds[nn * P2 + rem] = d * (1.0f / 3.0f);
    if (chunk == 0) {
      if (t >= 1) scores_new[gp] = S;
      lsum += d * d;
    }
  }
  lsum = waveSum(lsum);
  if ((tid & 63) == 0) lred[tid >> 6] = lsum;
  __syncthreads();
  if (chunk == 0 && tid == 0) {
    float L = 0.f;
#pragma unroll
    for (int i = 0; i < 16; ++i) L += lred[i];
    part[P_LOSS + t * NS + s] = L * (1.0f / 3.0f);
  }

  // ---- phase 2: build Rs [tap][k] f16 in LDS ----
  for (int idx = tid; idx < 16 * RSP; idx += 1024) {
    int tap = (unsigned)idx / (unsigned)RSP;
    int k = idx - tap * RSP;
    float val = 0.f;
    if (k < KTOT) {
      int n = k >> 9, uv = k & 511;
      if (uv < UV) {
        int u = (unsigned)uv / 22u;
        int v = uv - u * 22;
        int ky = tap >> 2, kx = tap & 3;
        int y = u + 2 - ky, x = v + 2 - kx;
        if ((unsigned)y < 23u && (unsigned)x < 23u) val = r_lds[n * P2 + y * OH + x];
      }
    }
    shp.rs[idx] = __half_as_ushort(__float2half(val));
  }
  __syncthreads();

  // ---- phase 3: MFMA GEMM, 4 M-tiles x 4 K-quarters (12 K-steps each) ----
  int wave = tid >> 6, lane = tid & 63;
  int q = lane >> 4, m16 = lane & 15;
  int tile = wave & 3, kq = wave >> 2;
  int c = c0 + tile * 16 + m16;
  const u16* brow = shp.rs + m16 * RSP + kq * 384 + q * 8;
  f32x4 acc = {0.f, 0.f, 0.f, 0.f};
  if (t == 0) {
#pragma unroll
    for (int ks = 0; ks < 12; ++ks) {
      int kb = kq * 12 + ks;
      int k0 = kb * 32 + q * 8;
      int nn = k0 >> 9, uv0 = k0 & 511;
      float v[8];
#pragma unroll
      for (int i = 0; i < 8; ++i) v[i] = 0.f;
      if (uv0 < UV) {
        const float* fsrc = feat + ((size_t)(nn * NS + s) * CHN + c) * UV + uv0;
        if (uv0 + 8 <= UV) {
          float4 p0 = *(const float4*)fsrc;
          float4 p1 = *(const float4*)(fsrc + 4);
          v[0] = p0.x; v[1] = p0.y; v[2] = p0.z; v[3] = p0.w;
          v[4] = p1.x; v[5] = p1.y; v[6] = p1.z; v[7] = p1.w;
        } else {  // uv0 == 480: 4 valid
#pragma unroll
          for (int i = 0; i < 4; ++i) v[i] = fsrc[i];
        }
      }
      union { u16 h[8]; f16x8 f; uint4 u; } av;
#pragma unroll
      for (int i = 0; i < 8; ++i) av.h[i] = __half_as_ushort(__float2half(v[i]));
      *(uint4*)(featC + (((size_t)(s * NKB + kb) * CHN + c) * 32 + q * 8)) = av.u;
      f16x8 bf = *(const f16x8*)(brow + ks * 32);
      acc = __builtin_amdgcn_mfma_f32_16x16x32_f16(av.f, bf, acc, 0, 0, 0);
    }
  } else {
    const u16* arow = featC + ((size_t)(s * NKB + kq * 12) * CHN + c) * 32 + q * 8;
#pragma unroll
    for (int ks = 0; ks < 12; ++ks) {
      f16x8 a = *(const f16x8*)(arow + (size_t)ks * (CHN * 32));
      f16x8 bf = *(const f16x8*)(brow + ks * 32);
      acc = __builtin_amdgcn_mfma_f32_16x16x32_f16(a, bf, acc, 0, 0, 0);
    }
  }
  if (kq) *(f32x4*)&kred[(((kq - 1) * 4 + tile) * 64 + lane) * 4] = acc;
  __syncthreads();

  // ---- phase 4: epilogue (kq==0 waves): w update, wg write, wgB LDS, partials ----
  float num_part = 0.f, wsq_part = 0.f;
  if (kq == 0) {
#pragma unroll
    for (int kk = 0; kk < 3; ++kk)
      acc += *(const f32x4*)&kred[((kk * 4 + tile) * 64 + lane) * 4];
    int tap = m16;
    int ccb = c0 + tile * 16 + q * 4;  // base c of this lane's 4 rows
    union { u16 h[4]; uint2 v2; } pk;
#pragma unroll
    for (int r = 0; r < 4; ++r) {
      int cc = ccb + r;
      size_t widx = (size_t)s * 8192 + (size_t)cc * 16 + tap;
      float wold = wmaster[widx];
      float wnew = wold;
      if (t >= 1) {
        wnew = wold - step * alpha_p * wg[widx];
        wmaster[widx] = wnew;
      }
      float wgn = acc[r] + reg * wnew;
      wg[widx] = wgn;
      pk.h[r] = __half_as_ushort(__float2half(wgn));
      wsq_part += wnew * wnew;
      num_part += wgn * wgn;
    }
    *(uint2*)&wgB[m16 * 72 + tile * 16 + q * 4] = pk.v2;
  }
  num_part = waveSum(num_part);
  wsq_part = waveSum(wsq_part);
  if (lane == 0) {
    nred[wave] = num_part;
    wred[wave] = wsq_part;
  }
  __syncthreads();  // wgB + nred/wred visible; rs reads done -> G may overwrite
  if (tid == 0) {
    float nsum = 0.f, wsum = 0.f;
#pragma unroll
    for (int i = 0; i < 16; ++i) {
      nsum += nred[i];
      wsum += wred[i];
    }
    part[P_NUM + (size_t)(t * NS + s) * 8 + chunk] = nsum;
    if (t >= 1) part[P_WSQA + (size_t)((t - 1) * NS + s) * 8 + chunk] = wsum;
  }

  // ---- phase 5: fused forward — partial scores for THIS chunk (A_chunk · wg_chunk) --
  f16x8 bf0 = *(const f16x8*)&wgB[m16 * 72 + q * 8];
  f16x8 bf1 = *(const f16x8*)&wgB[m16 * 72 + 32 + q * 8];
  int cbb = chunk >> 1;
  int chalf = (chunk & 1) * 64;
  for (int n = 0; n < 3; ++n) {
    if (n) __syncthreads();  // previous gather done -> G may be overwritten
    int snT = s * 3 + n;
    const u16* ab = featT + (size_t)(snT * 4 + cbb) * UV * 128 + chalf + q * 8;
    {
      int r0 = wave * 16 + m16;  // <= 255
      const u16* ap = ab + (size_t)r0 * 128;
      f32x4 a0 = {0.f, 0.f, 0.f, 0.f};
      a0 = __builtin_amdgcn_mfma_f32_16x16x32_f16(*(const f16x8*)ap, bf0, a0, 0, 0, 0);
      a0 = __builtin_amdgcn_mfma_f32_16x16x32_f16(*(const f16x8*)(ap + 32), bf1, a0, 0,
                                                  0, 0);
#pragma unroll
      for (int r = 0; r < 4; ++r) shp.G[(wave * 16 + q * 4 + r) * 17 + m16] = a0[r];
      if (wave < 15) {
        int r1 = (wave + 16) * 16 + m16;
        if (r1 > 483) r1 = 483;  // tile 30 pad rows: clamp (never gathered)
        const u16* ap1 = ab + (size_t)r1 * 128;
        f32x4 a1 = {0.f, 0.f, 0.f, 0.f};
        a1 = __builtin_amdgcn_mfma_f32_16x16x32_f16(*(const f16x8*)ap1, bf0, a1, 0, 0, 0);
        a1 = __builtin_amdgcn_mfma_f32_16x16x32_f16(*(const f16x8*)(ap1 + 32), bf1, a1,
                                                    0, 0, 0);
#pragma unroll
        for (int r = 0; r < 4; ++r)
          shp.G[((wave + 16) * 16 + q * 4 + r) * 17 + m16] = a1[r];
      }
    }
    __syncthreads();
    if (tid < P2) {
      int y = tid / 23, x = tid - y * 23;
      float val = 0.f;
#pragma unroll
      for (int ky = 0; ky < 4; ++ky) {
        int u = y + ky - 2;
        if ((unsigned)u < 22u) {
#pragma unroll
          for (int kx = 0; kx < 4; ++kx) {
            int v = x + kx - 2;
            if ((unsigned)v < 22u) val += shp.G[(u * 22 + v) * 17 + ky * 4 + kx];
          }
        }
      }
      sgp[(size_t)chunk * NP + (size_t)(n * NS + s) * P2 + tid] = val;
    }
  }
}

// ---------------- k_den: per-s sum of sgraw4^2 (for k_final's alpha4) --------------
__global__ __launch_bounds__(1024) void k_den(const float* __restrict__ sgp,
                                              float* __restrict__ part) {
  __shared__ float dend[16];
  int s = blockIdx.x, tid = threadIdx.x;
  float dp = 0.f;
  for (int pl = tid; pl < 1587; pl += 1024) {
    int nn = (unsigned)pl / (unsigned)P2;
    int rem = pl - nn * P2;
    size_t gp = (size_t)(nn * NS + s) * P2 + rem;
    float g = 0.f;
#pragma unroll
    for (int ch = 0; ch < 8; ++ch) g += sgp[(size_t)ch * NP + gp];
    dp += g * g;
  }
  dp = waveSum(dp);
  if ((tid & 63) == 0) dend[tid >> 6] = dp;
  __syncthreads();
  if (tid == 0) {
    float de = 0.f;
#pragma unroll
    for (int i = 0; i < 16; ++i) de += dend[i];
    part[P_DEN + s] = de * (1.0f / 3.0f);
  }
}

__device__ __forceinline__ float alphaFinal(const float* __restrict__ part, int s,
                                            float reg) {
  const float* np_ = part + P_NUM + (size_t)(4 * NS + s) * 8;
  float nu = 0.f;
#pragma unroll
  for (int i = 0; i < 8; ++i) nu += np_[i];
  float de = part[P_DEN + s];
  return nu / fmaxf(de + reg * nu, 1e-8f);
}

// ---------------- final: w5 update + final residual loss parts ----------------
__global__ void k_final(float* __restrict__ wmaster, const float* __restrict__ wg,
                        const float* __restrict__ scores4, const float* __restrict__ sgp,
                        const float* __restrict__ label, float* __restrict__ part,
                        const float* __restrict__ lsl, const float* __restrict__ fr) {
  __shared__ float alpha_s[32];
  __shared__ float red4[4];
  int b = blockIdx.x, tid = threadIdx.x;
  float step = __expf(lsl[0]);
  float frv = fr[0];
  float reg = fmaxf(frv * frv, 1e-6f);
  if (tid < 32) alpha_s[tid] = alphaFinal(part, tid, reg);
  __syncthreads();
  if (b < 1024) {
    int idx = b * 256 + tid;  // 1024*256 == 262144 exactly
    int s = idx >> 13;        // uniform per block
    float w5 = wmaster[idx] - step * alpha_s[s] * wg[idx];
    wmaster[idx] = w5;
    float sq = waveSum(w5 * w5);
    if ((tid & 63) == 0) red4[tid >> 6] = sq;
    __syncthreads();
    if (tid == 0) part[P_WSQ5 + b] = red4[0] + red4[1] + red4[2] + red4[3];
  } else {
    int p = (b - 1024) * 256 + tid;
    float contrib = 0.f;
    if (p < NP) {
      int nsid = p / P2;
      int s = nsid & 31;  // nsid = n*NS + s
      float g = 0.f;
#pragma unroll
      for (int ch = 0; ch < 8; ++ch) g += sgp[(size_t)ch * NP + p];
      float s5 = scores4[p] - step * alpha_s[s] * g;
      float d = s5 - label[p];
      contrib = d * d;
    }
    contrib = waveSum(contrib);
    if ((tid & 63) == 0) red4[tid >> 6] = contrib;
    __syncthreads();
    if (tid == 0)
      part[P_L5 + (b - 1024)] = (red4[0] + red4[1] + red4[2] + red4[3]) * (1.0f / 3.0f);
  }
}

// ---------------- losses: deterministic sums of all partials ----------------
__global__ void k_losses(float* __restrict__ out_losses, const float* __restrict__ part,
                         const float* __restrict__ fr) {
  __shared__ float red[8];
  int tid = threadIdx.x;  // 256
  float frv = fr[0];
  float reg = fmaxf(frv * frv, 1e-6f);
  float v5 = 0.f;
  for (int i = tid; i < 1024; i += 256) v5 += part[P_WSQ5 + i];
  v5 = waveSum(v5);
  if ((tid & 63) == 0) red[tid >> 6] = v5;
  __syncthreads();
  float wsq5 = red[0] + red[1] + red[2] + red[3];
  float l5 = 0.f;
  for (int i = tid; i < 199; i += 256) l5 += part[P_L5 + i];
  l5 = waveSum(l5);
  if ((tid & 63) == 0) red[4 + (tid >> 6)] = l5;
  __syncthreads();
  float loss5 = red[4] + red[5] + red[6] + red[7];
  if (tid < 5) {
    int t = tid;
    float ls = 0.f;
    for (int i = 0; i < 32; ++i) ls += part[P_LOSS + t * NS + i];
    float ws_ = 0.f;
    if (t == 0) {
      for (int i = 0; i < 32; ++i) ws_ += part[P_WSQ0 + i];
    } else {
      for (int i = 0; i < 256; ++i) ws_ += part[P_WSQA + (t - 1) * 256 + i];
    }
    out_losses[t] = (ls + reg * ws_) * (1.0f / 32.0f);
  }
  if (tid == 5) out_losses[5] = (loss5 + reg * wsq5) * (1.0f / 32.0f);
}

// ---------------- launch ----------------
extern "C" void kernel_launch(void* const* d_in, const int* in_sizes, int n_in,
                              void* d_out, int out_size, void* d_ws, size_t ws_size,
                              hipStream_t stream) {
  const float* w0 = (const float*)d_in[0];
  const float* feat = (const float*)d_in[1];
  const float* bb = (const float*)d_in[2];
  const float* lsl = (const float*)d_in[3];
  const float* fr = (const float*)d_in[4];
  float* out = (float*)d_out;
  char* ws = (char*)d_ws;
  u16* featT = (u16*)(ws + OFF_FEATT);
  float* label = (float*)(ws + OFF_LABEL);
  float* s0 = (float*)(ws + OFF_S0);
  float* s0b = (float*)(ws + OFF_S0B);
  float* s1 = (float*)(ws + OFF_S1);
  float* sgp = (float*)(ws + OFF_SGP);
  float* wg = (float*)(ws + OFF_WG);
  u16* w0f16 = (u16*)(ws + OFF_W0F16);
  float* part = (float*)(ws + OFF_PART);
  u16* featC = (u16*)(ws + OFF_FEATC);

  k_setup<<<1668, 512, 0, stream>>>(feat, w0, bb, featT, w0f16, out, label, part);
  // initial scores_0 partials = A * w0  (A half / B half)
  k_conv_fwd<<<192, 1024, 0, stream>>>(featT, w0f16, s0, s0b);
  // adjoint(t) also produces sgp = per-chunk partials of A·wg_t (fused forward)
  for (int t = 0; t < 5; ++t) {
    const float* so = (t <= 1) ? s0 : ((t & 1) ? s0 : s1);  // t=2,4 read s1; t=3 reads s0
    float* sn = (t & 1) ? s1 : s0;                          // t=1->s1, t=2->s0, ...
    k_adjoint<<<256, 1024, 0, stream>>>(t, feat, featT, featC, label, s0, s0b, so, sn,
                                        sgp, wg, out, part, lsl, fr);
  }
  // merged scores_4 lives in s0 (t=4 wrote sn=s0); sgraw4 partials in sgp
  k_den<<<32, 1024, 0, stream>>>(sgp, part);
  k_final<<<1223, 256, 0, stream>>>(out, wg, s0, sgp, label, part, lsl, fr);
  k_losses<<<1, 256, 0, stream>>>(out + WSZ, part, fr);
}